// Round 5
// baseline (47.443 us; speedup 1.0000x reference)
//
#include <hip/hip_runtime.h>

constexpr int OBS   = 682;   // 210 view + 32 feat + 440 nb
constexpr int ACTN  = 21;
constexpr int C1W_N = 1440;  // 32*5*3*3
constexpr int C2W_N = 9216;  // 32*32*3*3

// Transpose conv weights: [oc][k] -> [k][oc]  (k = c*9 + kh*3 + kw)
__global__ void transpose_w_k(const float* __restrict__ c1w,
                              const float* __restrict__ c2w,
                              float* __restrict__ ws) {
    int idx = blockIdx.x * 256 + threadIdx.x;
    if (idx < C1W_N) {
        int oc = idx / 45, x = idx - oc * 45;
        ws[x * 32 + oc] = c1w[idx];
    }
    int i2 = idx - C1W_N;
    if (i2 >= 0 && i2 < C2W_N) {
        int oc = i2 / 288, x = i2 - oc * 288;
        ws[C1W_N + x * 32 + oc] = c2w[i2];
    }
}

__device__ __forceinline__ float comp4(float4 v, int i) {
    return (i == 0) ? v.x : (i == 1) ? v.y : (i == 2) ? v.z : v.w;
}

// LDS arena (float offsets)
constexpr int S_OBS  = 0;     // 682
constexpr int S_C1   = 688;   // 640  [ic][h=5][w=4]
constexpr int S_PART = 1328;  // 768  [q][oc*6+p]  (conv2 partials)
constexpr int S_F1P  = 1328;  // 128  (reuses PART after conv2 reduce)
constexpr int S_BP   = 1456;  // 128
constexpr int S_BASE = 1584;  // 64
constexpr int S_HP   = 1648;  // 128
constexpr int S_CNT  = 1776;  // 2
constexpr int S_C2   = 2096;  // 192  [oc][pos=6]
constexpr int S_X    = 2288;  // 64
constexpr int S_H    = 2352;  // 64
constexpr int S_TOT  = 2416;

template <bool TW>
__global__ __launch_bounds__(128, 8) void fused_k(
    const float* __restrict__ obs,
    const float* __restrict__ c1w, const float* __restrict__ c1b,
    const float* __restrict__ c2w, const float* __restrict__ c2b,
    const float* __restrict__ f1w, const float* __restrict__ f1b,
    const float* __restrict__ f2w, const float* __restrict__ f2b,
    const float* __restrict__ f3w, const float* __restrict__ f3b,
    const float* __restrict__ wt,
    float* __restrict__ out)
{
    const int b = blockIdx.x;
    const int t = threadIdx.x;
    const int w = t >> 6;        // wave id 0/1
    const int l = t & 63;        // lane in wave

    __shared__ __align__(16) float sb[S_TOT];
    __shared__ int s_meta[20];

    // ---- stage obs row (float2; row base 8B-aligned since 682 even) ----
    {
        const float2* src = (const float2*)(obs + (long)b * OBS);
        float2* dst = (float2*)sb;
        for (int i = t; i < 341; i += 128) dst[i] = src[i];
    }
    __syncthreads();

    // ---- agent meta scan (acts one-hot or zero) ----
    if (t < 20) {
        const float* nb = &sb[S_OBS + 242 + t * 22];
        int id = (int)nb[0];
        int js = -1;
        #pragma unroll
        for (int j = 0; j < ACTN; ++j) {
            float av = nb[1 + j];
            js = (av != 0.f && js < 0) ? j : js;
        }
        int mode = (id < -1) ? 0 : ((id >= 0 && js < 0) ? 1 : 2);
        s_meta[t] = ((id + 2) << 8) | (mode << 5) | (js + 1);
    }

    // ---- conv1: (5,7,6) -> (32,5,4), relu; lane = (oc, ow), 5 outputs ----
    {
        const int oc = t & 31, ow = t >> 5;    // ow in 0..3
        float acc[5];
        #pragma unroll
        for (int i = 0; i < 5; ++i) acc[i] = 0.f;
        #pragma unroll
        for (int c = 0; c < 5; ++c) {
            float wv[9];
            #pragma unroll
            for (int k = 0; k < 9; ++k)
                wv[k] = TW ? wt[(c * 9 + k) * 32 + oc] : c1w[oc * 45 + c * 9 + k];
            #pragma unroll
            for (int r = 0; r < 7; ++r) {
                float rv0 = sb[S_OBS + c * 42 + r * 6 + ow];
                float rv1 = sb[S_OBS + c * 42 + r * 6 + ow + 1];
                float rv2 = sb[S_OBS + c * 42 + r * 6 + ow + 2];
                #pragma unroll
                for (int kh = 0; kh < 3; ++kh) {
                    int oh = r - kh;
                    if (oh < 0 || oh > 4) continue;       // compile-time after unroll
                    acc[oh] = fmaf(rv0, wv[kh * 3 + 0], acc[oh]);
                    acc[oh] = fmaf(rv1, wv[kh * 3 + 1], acc[oh]);
                    acc[oh] = fmaf(rv2, wv[kh * 3 + 2], acc[oh]);
                }
            }
        }
        float bias = c1b[oc];
        #pragma unroll
        for (int oh = 0; oh < 5; ++oh)
            sb[S_C1 + oc * 20 + oh * 4 + ow] = fmaxf(acc[oh] + bias, 0.f);
    }
    __syncthreads();

    // ---- conv2: (32,5,4) -> (32,3,2); lane = (oc, q); q = ic-quarter ----
    {
        const int oc = t & 31, q = t >> 5;     // q in 0..3 -> ic q*8..q*8+7
        float a0 = 0.f, a1 = 0.f, a2 = 0.f, a3 = 0.f, a4 = 0.f, a5 = 0.f; // p = oh*2+ow
        #pragma unroll 2
        for (int icc = 0; icc < 8; ++icc) {
            const int ic = q * 8 + icc;
            const float4* rp = (const float4*)&sb[S_C1 + ic * 20];
            float4 r0 = rp[0], r1 = rp[1], r2 = rp[2], r3 = rp[3], r4 = rp[4];
            float wv[9];
            #pragma unroll
            for (int k = 0; k < 9; ++k)
                wv[k] = TW ? wt[C1W_N + (ic * 9 + k) * 32 + oc] : c2w[oc * 288 + ic * 9 + k];
            #pragma unroll
            for (int kh = 0; kh < 3; ++kh) {
                float4 ra = (kh == 0) ? r0 : (kh == 1) ? r1 : r2;   // row kh   (oh=0)
                float4 rb = (kh == 0) ? r1 : (kh == 1) ? r2 : r3;   // row kh+1 (oh=1)
                float4 rc = (kh == 0) ? r2 : (kh == 1) ? r3 : r4;   // row kh+2 (oh=2)
                #pragma unroll
                for (int kw = 0; kw < 3; ++kw) {
                    float ww = wv[kh * 3 + kw];
                    a0 = fmaf(comp4(ra, kw),     ww, a0);
                    a1 = fmaf(comp4(ra, kw + 1), ww, a1);
                    a2 = fmaf(comp4(rb, kw),     ww, a2);
                    a3 = fmaf(comp4(rb, kw + 1), ww, a3);
                    a4 = fmaf(comp4(rc, kw),     ww, a4);
                    a5 = fmaf(comp4(rc, kw + 1), ww, a5);
                }
            }
        }
        float* pp = &sb[S_PART + q * 192 + oc * 6];
        pp[0] = a0; pp[1] = a1; pp[2] = a2; pp[3] = a3; pp[4] = a4; pp[5] = a5;
    }
    __syncthreads();
    // reduce 4 partials -> s_c2
    for (int i = t; i < 192; i += 128) {
        int oc = i / 6;
        float v = sb[S_PART + i] + sb[S_PART + 192 + i] + sb[S_PART + 384 + i] + sb[S_PART + 576 + i];
        sb[S_C2 + i] = fmaxf(v + c2b[oc], 0.f);
    }
    __syncthreads();

    // ---- fc1: 192 -> 64, relu; k-split across waves ----
    {
        float a0 = 0.f, a1 = 0.f;
        const float4* xp = (const float4*)&sb[S_C2 + w * 96];
        const float* wbase = f1w + (w * 96) * 64 + l;
        #pragma unroll 4
        for (int i4 = 0; i4 < 24; ++i4) {
            float4 v = xp[i4];
            a0 = fmaf(v.x, wbase[(i4 * 4 + 0) * 64], a0);
            a1 = fmaf(v.y, wbase[(i4 * 4 + 1) * 64], a1);
            a0 = fmaf(v.z, wbase[(i4 * 4 + 2) * 64], a0);
            a1 = fmaf(v.w, wbase[(i4 * 4 + 3) * 64], a1);
        }
        sb[S_F1P + w * 64 + l] = a0 + a1;
    }
    __syncthreads();
    if (t < 64)
        sb[S_X + t] = fmaxf(sb[S_F1P + t] + sb[S_F1P + 64 + t] + f1b[t], 0.f);
    __syncthreads();

    // ---- base: wave0 = x@W2x, wave1 = feat@W2f ----
    {
        float a0 = 0.f, a1 = 0.f;
        if (w == 0) {
            const float* W2x = f2w;                 // rows [0,64)
            const float4* xp = (const float4*)&sb[S_X];
            #pragma unroll 4
            for (int i4 = 0; i4 < 16; ++i4) {
                float4 v = xp[i4];
                a0 = fmaf(v.x, W2x[(i4 * 4 + 0) * 64 + l], a0);
                a1 = fmaf(v.y, W2x[(i4 * 4 + 1) * 64 + l], a1);
                a0 = fmaf(v.z, W2x[(i4 * 4 + 2) * 64 + l], a0);
                a1 = fmaf(v.w, W2x[(i4 * 4 + 3) * 64 + l], a1);
            }
        } else {
            const float* W2f = f2w + 64 * 64;       // rows [64,96)
            const float2* fp = (const float2*)&sb[S_OBS + 210];
            #pragma unroll 4
            for (int i2 = 0; i2 < 16; ++i2) {
                float2 v = fp[i2];
                a0 = fmaf(v.x, W2f[(i2 * 2 + 0) * 64 + l], a0);
                a1 = fmaf(v.y, W2f[(i2 * 2 + 1) * 64 + l], a1);
            }
        }
        sb[S_BP + w * 64 + l] = a0 + a1;
    }
    __syncthreads();
    if (t < 64)
        sb[S_BASE + t] = sb[S_BP + t] + sb[S_BP + 64 + t] + f2b[t];
    __syncthreads();

    // ---- agents: 10 per wave ----
    {
        const float* W2id  = f2w + 96 * 64;
        const float* W2act = f2w + 116 * 64;
        const float base_l = sb[S_BASE + l];
        float hacc = 0.f, cnt = 0.f;
        const int a0i = w * 10;
        for (int a = a0i; a < a0i + 10; ++a) {
            int m = s_meta[a];
            int mode = (m >> 5) & 3;
            if (mode == 0) continue;               // wave-uniform skip
            int id = (m >> 8) - 2;
            int js = (m & 31) - 1;
            float u = base_l + ((id >= 0) ? W2id[id * 64 + l] : 0.f);
            if (mode == 1) {                        // expand: sum_j relu(u + W2act[j])
                float h0 = 0.f, h1 = 0.f, h2 = 0.f;
                #pragma unroll
                for (int j = 0; j < ACTN; j += 3) {
                    h0 += fmaxf(u + W2act[(j    ) * 64 + l], 0.f);
                    h1 += fmaxf(u + W2act[(j + 1) * 64 + l], 0.f);
                    h2 += fmaxf(u + W2act[(j + 2) * 64 + l], 0.f);
                }
                hacc += (h0 + h1) + h2;
                cnt  += 21.f;
            } else {                                // single action (or none, id==-1)
                float ar = (js >= 0) ? W2act[js * 64 + l] : 0.f;
                hacc += fmaxf(u + ar, 0.f);
                cnt  += 1.f;
            }
        }
        sb[S_HP + w * 64 + l] = hacc;
        if (l == 0) sb[S_CNT + w] = cnt;
    }
    __syncthreads();
    if (t < 64) sb[S_H + t] = sb[S_HP + t] + sb[S_HP + 64 + t];
    __syncthreads();

    // ---- final: q = h @ fc3_w + cnt*fc3_b ----
    if (t < ACTN) {
        float cntT = sb[S_CNT] + sb[S_CNT + 1];
        float q0 = cntT * f3b[t], q1 = 0.f;
        const float4* hp = (const float4*)&sb[S_H];
        #pragma unroll 4
        for (int h4 = 0; h4 < 16; ++h4) {
            float4 v = hp[h4];
            q0 = fmaf(v.x, f3w[(h4 * 4 + 0) * 21 + t], q0);
            q1 = fmaf(v.y, f3w[(h4 * 4 + 1) * 21 + t], q1);
            q0 = fmaf(v.z, f3w[(h4 * 4 + 2) * 21 + t], q0);
            q1 = fmaf(v.w, f3w[(h4 * 4 + 3) * 21 + t], q1);
        }
        out[b * 21 + t] = q0 + q1;
    }
}

extern "C" void kernel_launch(void* const* d_in, const int* in_sizes, int n_in,
                              void* d_out, int out_size, void* d_ws, size_t ws_size,
                              hipStream_t stream) {
    const float* obs = (const float*)d_in[0];
    const float* c1w = (const float*)d_in[1];
    const float* c1b = (const float*)d_in[2];
    const float* c2w = (const float*)d_in[3];
    const float* c2b = (const float*)d_in[4];
    const float* f1w = (const float*)d_in[5];
    const float* f1b = (const float*)d_in[6];
    const float* f2w = (const float*)d_in[7];
    const float* f2b = (const float*)d_in[8];
    const float* f3w = (const float*)d_in[9];
    const float* f3b = (const float*)d_in[10];
    float* ws = (float*)d_ws;
    float* o  = (float*)d_out;

    const bool tw = ws_size >= (size_t)(C1W_N + C2W_N) * sizeof(float);
    if (tw) {
        transpose_w_k<<<(C1W_N + C2W_N + 255) / 256, 256, 0, stream>>>(c1w, c2w, ws);
        fused_k<true><<<4096, 128, 0, stream>>>(obs, c1w, c1b, c2w, c2b, f1w, f1b,
                                                f2w, f2b, f3w, f3b, ws, o);
    } else {
        fused_k<false><<<4096, 128, 0, stream>>>(obs, c1w, c1b, c2w, c2b, f1w, f1b,
                                                 f2w, f2b, f3w, f3b, ws, o);
    }
}

// Round 6
// 41.473 us; speedup vs baseline: 1.1440x; 1.1440x over previous
//
#include <hip/hip_runtime.h>

constexpr int OBS  = 682;   // 210 view + 32 feat + 440 nb
constexpr int ACTN = 21;

// ---- repacked weight arena (float4-unit offsets in d_ws) ----
constexpr int C1P  = 0;     // [c][oc][3]   480 f4
constexpr int C2P  = 480;   // [ic][oc][3]  3072 f4
constexpr int F1P  = 3552;  // [kq<48][t]   3072 f4
constexpr int W2XP = 6624;  // [kq<16][t]   1024 f4
constexpr int W2FP = 7648;  // [kq<8][t]    512 f4
constexpr int F3P  = 8160;  // [hq<16][a21] 336 f4
constexpr int WS_F4 = 8496;

__global__ void repack_k(const float* __restrict__ c1w, const float* __restrict__ c2w,
                         const float* __restrict__ f1w, const float* __restrict__ f2w,
                         const float* __restrict__ f3w, float4* __restrict__ ws4) {
    int q = blockIdx.x * 256 + threadIdx.x;
    if (q >= WS_F4) return;
    float v[4];
    if (q < C2P) {                                    // conv1 [c][oc][3]
        int c = q / 96, rem = q % 96, oc = rem / 3, part = rem % 3;
        #pragma unroll
        for (int r = 0; r < 4; ++r) {
            int k = 4 * part + r;
            v[r] = (k < 9) ? c1w[oc * 45 + c * 9 + k] : 0.f;
        }
    } else if (q < F1P) {                             // conv2 [ic][oc][3]
        int i = q - C2P;
        int ic = i / 96, rem = i % 96, oc = rem / 3, part = rem % 3;
        #pragma unroll
        for (int r = 0; r < 4; ++r) {
            int k = 4 * part + r;
            v[r] = (k < 9) ? c2w[oc * 288 + ic * 9 + k] : 0.f;
        }
    } else if (q < W2XP) {                            // fc1 [kq][t]
        int i = q - F1P, kq = i >> 6, t = i & 63;
        #pragma unroll
        for (int r = 0; r < 4; ++r) v[r] = f1w[(4 * kq + r) * 64 + t];
    } else if (q < W2FP) {                            // W2x rows [0,64)
        int i = q - W2XP, kq = i >> 6, t = i & 63;
        #pragma unroll
        for (int r = 0; r < 4; ++r) v[r] = f2w[(4 * kq + r) * 64 + t];
    } else if (q < F3P) {                             // W2f rows [64,96)
        int i = q - W2FP, kq = i >> 6, t = i & 63;
        #pragma unroll
        for (int r = 0; r < 4; ++r) v[r] = f2w[(64 + 4 * kq + r) * 64 + t];
    } else {                                          // fc3 [hq][a]
        int i = q - F3P, hq = i / 21, a = i % 21;
        #pragma unroll
        for (int r = 0; r < 4; ++r) v[r] = f3w[(4 * hq + r) * 21 + a];
    }
    ws4[q] = make_float4(v[0], v[1], v[2], v[3]);
}

__device__ __forceinline__ float comp4(float4 v, int i) {
    return (i == 0) ? v.x : (i == 1) ? v.y : (i == 2) ? v.z : v.w;
}

// LDS arena (float offsets)
constexpr int S_V    = 0;     // 280: padded view [c][r][8] (cols 0..5 valid)
constexpr int S_OBS  = 280;   // 682: flat obs; only [210,682) (feat|nb) used
constexpr int S_C1   = 968;   // 640  [ic][h=5][w=4]
constexpr int S_PART = 1608;  // 384  [half][oc][6]
constexpr int S_C2   = 1992;  // 192  [oc][pos=6]
constexpr int S_X    = 2184;  // 64
constexpr int S_H    = 2248;  // 64
constexpr int S_TOT  = 2312;

template <bool TW>
__global__ __launch_bounds__(64, 4) void fused_k(
    const float* __restrict__ obs,
    const float* __restrict__ c1w, const float* __restrict__ c1b,
    const float* __restrict__ c2w, const float* __restrict__ c2b,
    const float* __restrict__ f1w, const float* __restrict__ f1b,
    const float* __restrict__ f2w, const float* __restrict__ f2b,
    const float* __restrict__ f3w, const float* __restrict__ f3b,
    const float* __restrict__ wt,
    float* __restrict__ out)
{
    const int b = blockIdx.x;
    const int t = threadIdx.x;

    __shared__ __align__(16) float sb[S_TOT];
    __shared__ int s_meta[20];
    const float4* wp = (const float4*)wt;

    // ---- stage: view -> padded [c][r][8]; feat|nb -> flat ----
    {
        const float* orow = obs + (long)b * OBS;
        #pragma unroll
        for (int k = 0; k < 4; ++k) {
            int i = t + k * 64;
            if (i < 210) {
                int c = i / 42, rem = i - 42 * c;
                int r = rem / 6, col = rem - 6 * r;
                sb[S_V + c * 56 + r * 8 + col] = orow[i];
            }
        }
        #pragma unroll
        for (int k = 0; k < 8; ++k) {
            int i = 210 + t + k * 64;
            if (i < OBS) sb[S_OBS + i] = orow[i];
        }
    }
    __syncthreads();

    // ---- agent meta scan (acts one-hot or zero) ----
    if (t < 20) {
        const float* nb = &sb[S_OBS + 242 + t * 22];
        int id = (int)nb[0];
        int js = -1;
        #pragma unroll
        for (int j = 0; j < ACTN; ++j) {
            float av = nb[1 + j];
            js = (av != 0.f && js < 0) ? j : js;
        }
        int mode = (id < -1) ? 0 : ((id >= 0 && js < 0) ? 1 : 2);
        s_meta[t] = ((id + 2) << 8) | (mode << 5) | (js + 1);
    }

    // ---- conv1: lane=(oc,s); outputs oh in {2s,2s+1,2s+2} x ow 0..3 ----
    {
        const int oc = t & 31, s = t >> 5;
        float acc[12];                        // [oh_l][ow]
        #pragma unroll
        for (int i = 0; i < 12; ++i) acc[i] = 0.f;
        #pragma unroll
        for (int c = 0; c < 5; ++c) {
            float w[9];
            if constexpr (TW) {
                float4 w0 = wp[C1P + c * 96 + oc * 3 + 0];
                float4 w1 = wp[C1P + c * 96 + oc * 3 + 1];
                float4 w2 = wp[C1P + c * 96 + oc * 3 + 2];
                w[0] = w0.x; w[1] = w0.y; w[2] = w0.z; w[3] = w0.w;
                w[4] = w1.x; w[5] = w1.y; w[6] = w1.z; w[7] = w1.w;
                w[8] = w2.x;
            } else {
                #pragma unroll
                for (int k = 0; k < 9; ++k) w[k] = c1w[oc * 45 + c * 9 + k];
            }
            #pragma unroll
            for (int rr = 0; rr < 5; ++rr) {
                const float* rowp = &sb[S_V + c * 56 + (2 * s + rr) * 8];
                float4 v0 = *(const float4*)rowp;
                float2 v1 = *(const float2*)(rowp + 4);
                float col0 = v0.x, col1 = v0.y, col2 = v0.z, col3 = v0.w;
                float col4 = v1.x, col5 = v1.y;
                #pragma unroll
                for (int kh = 0; kh < 3; ++kh) {
                    int ohl = rr - kh;
                    if (ohl < 0 || ohl > 2) continue;   // compile-time after unroll
                    acc[ohl * 4 + 0] = fmaf(col0, w[kh * 3 + 0], acc[ohl * 4 + 0]);
                    acc[ohl * 4 + 0] = fmaf(col1, w[kh * 3 + 1], acc[ohl * 4 + 0]);
                    acc[ohl * 4 + 0] = fmaf(col2, w[kh * 3 + 2], acc[ohl * 4 + 0]);
                    acc[ohl * 4 + 1] = fmaf(col1, w[kh * 3 + 0], acc[ohl * 4 + 1]);
                    acc[ohl * 4 + 1] = fmaf(col2, w[kh * 3 + 1], acc[ohl * 4 + 1]);
                    acc[ohl * 4 + 1] = fmaf(col3, w[kh * 3 + 2], acc[ohl * 4 + 1]);
                    acc[ohl * 4 + 2] = fmaf(col2, w[kh * 3 + 0], acc[ohl * 4 + 2]);
                    acc[ohl * 4 + 2] = fmaf(col3, w[kh * 3 + 1], acc[ohl * 4 + 2]);
                    acc[ohl * 4 + 2] = fmaf(col4, w[kh * 3 + 2], acc[ohl * 4 + 2]);
                    acc[ohl * 4 + 3] = fmaf(col3, w[kh * 3 + 0], acc[ohl * 4 + 3]);
                    acc[ohl * 4 + 3] = fmaf(col4, w[kh * 3 + 1], acc[ohl * 4 + 3]);
                    acc[ohl * 4 + 3] = fmaf(col5, w[kh * 3 + 2], acc[ohl * 4 + 3]);
                }
            }
        }
        float bias = c1b[oc];
        #pragma unroll
        for (int ohl = 0; ohl < 3; ++ohl) {
            int oh = 2 * s + ohl;                 // oh==2 dup-written identically
            float4 o4 = make_float4(fmaxf(acc[ohl * 4 + 0] + bias, 0.f),
                                    fmaxf(acc[ohl * 4 + 1] + bias, 0.f),
                                    fmaxf(acc[ohl * 4 + 2] + bias, 0.f),
                                    fmaxf(acc[ohl * 4 + 3] + bias, 0.f));
            *(float4*)&sb[S_C1 + oc * 20 + oh * 4] = o4;
        }
    }
    __syncthreads();

    // ---- conv2: (32,5,4) -> (32,3,2); lane=(oc,half) over ic halves ----
    {
        const int oc = t & 31, half = t >> 5;
        float a0 = 0.f, a1 = 0.f, a2 = 0.f, a3 = 0.f, a4 = 0.f, a5 = 0.f;
        #pragma unroll 4
        for (int icc = 0; icc < 16; ++icc) {
            const int ic = half * 16 + icc;
            const float4* rp = (const float4*)&sb[S_C1 + ic * 20];
            float4 r0 = rp[0], r1 = rp[1], r2 = rp[2], r3 = rp[3], r4 = rp[4];
            float w[9];
            if constexpr (TW) {
                float4 w0 = wp[C2P + ic * 96 + oc * 3 + 0];
                float4 w1 = wp[C2P + ic * 96 + oc * 3 + 1];
                float4 w2 = wp[C2P + ic * 96 + oc * 3 + 2];
                w[0] = w0.x; w[1] = w0.y; w[2] = w0.z; w[3] = w0.w;
                w[4] = w1.x; w[5] = w1.y; w[6] = w1.z; w[7] = w1.w;
                w[8] = w2.x;
            } else {
                #pragma unroll
                for (int k = 0; k < 9; ++k) w[k] = c2w[oc * 288 + ic * 9 + k];
            }
            #pragma unroll
            for (int kh = 0; kh < 3; ++kh) {
                float4 ra = (kh == 0) ? r0 : (kh == 1) ? r1 : r2;
                float4 rb = (kh == 0) ? r1 : (kh == 1) ? r2 : r3;
                float4 rc = (kh == 0) ? r2 : (kh == 1) ? r3 : r4;
                #pragma unroll
                for (int kw = 0; kw < 3; ++kw) {
                    float ww = w[kh * 3 + kw];
                    a0 = fmaf(comp4(ra, kw),     ww, a0);
                    a1 = fmaf(comp4(ra, kw + 1), ww, a1);
                    a2 = fmaf(comp4(rb, kw),     ww, a2);
                    a3 = fmaf(comp4(rb, kw + 1), ww, a3);
                    a4 = fmaf(comp4(rc, kw),     ww, a4);
                    a5 = fmaf(comp4(rc, kw + 1), ww, a5);
                }
            }
        }
        float* pp = &sb[S_PART + (half * 32 + oc) * 6];
        pp[0] = a0; pp[1] = a1; pp[2] = a2; pp[3] = a3; pp[4] = a4; pp[5] = a5;
    }
    __syncthreads();
    if (t < 32) {
        float bias = c2b[t];
        #pragma unroll
        for (int p = 0; p < 6; ++p)
            sb[S_C2 + t * 6 + p] = fmaxf(sb[S_PART + t * 6 + p] + sb[S_PART + (32 + t) * 6 + p] + bias, 0.f);
    }
    __syncthreads();

    // ---- fc1: 192 -> 64, relu ----
    {
        float a0 = f1b[t], a1 = 0.f;
        const float4* xp = (const float4*)&sb[S_C2];
        #pragma unroll 4
        for (int kq = 0; kq < 48; ++kq) {
            float4 x = xp[kq];
            float4 w;
            if constexpr (TW) w = wp[F1P + kq * 64 + t];
            else w = make_float4(f1w[(4*kq+0)*64+t], f1w[(4*kq+1)*64+t],
                                 f1w[(4*kq+2)*64+t], f1w[(4*kq+3)*64+t]);
            a0 = fmaf(x.x, w.x, a0);
            a1 = fmaf(x.y, w.y, a1);
            a0 = fmaf(x.z, w.z, a0);
            a1 = fmaf(x.w, w.w, a1);
        }
        sb[S_X + t] = fmaxf(a0 + a1, 0.f);
    }
    __syncthreads();

    // ---- base = x@W2x + feat@W2f + b2 ----
    float base_t;
    {
        float a0 = f2b[t], a1 = 0.f;
        const float4* xp = (const float4*)&sb[S_X];
        #pragma unroll 4
        for (int kq = 0; kq < 16; ++kq) {
            float4 x = xp[kq];
            float4 w;
            if constexpr (TW) w = wp[W2XP + kq * 64 + t];
            else w = make_float4(f2w[(4*kq+0)*64+t], f2w[(4*kq+1)*64+t],
                                 f2w[(4*kq+2)*64+t], f2w[(4*kq+3)*64+t]);
            a0 = fmaf(x.x, w.x, a0);
            a1 = fmaf(x.y, w.y, a1);
            a0 = fmaf(x.z, w.z, a0);
            a1 = fmaf(x.w, w.w, a1);
        }
        const float2* fp = (const float2*)&sb[S_OBS + 210];   // 8B-aligned (490 even)
        #pragma unroll 4
        for (int kq = 0; kq < 8; ++kq) {
            float2 x0 = fp[kq * 2], x1 = fp[kq * 2 + 1];
            float4 w;
            if constexpr (TW) w = wp[W2FP + kq * 64 + t];
            else w = make_float4(f2w[(64+4*kq+0)*64+t], f2w[(64+4*kq+1)*64+t],
                                 f2w[(64+4*kq+2)*64+t], f2w[(64+4*kq+3)*64+t]);
            a0 = fmaf(x0.x, w.x, a0);
            a1 = fmaf(x0.y, w.y, a1);
            a0 = fmaf(x1.x, w.z, a0);
            a1 = fmaf(x1.y, w.w, a1);
        }
        base_t = a0 + a1;
    }

    // ---- agents (meta-driven) ----
    const float* W2id  = f2w + 96 * 64;
    const float* W2act = f2w + 116 * 64;
    float hacc = 0.f, cnt = 0.f;
    for (int a = 0; a < 20; ++a) {
        int m = s_meta[a];
        int mode = (m >> 5) & 3;
        if (mode == 0) continue;               // wave-uniform skip
        int id = (m >> 8) - 2;
        int js = (m & 31) - 1;
        float u = base_t + ((id >= 0) ? W2id[id * 64 + t] : 0.f);
        if (mode == 1) {                        // expand: sum_j relu(u + W2act[j])
            float h0 = 0.f, h1 = 0.f, h2 = 0.f;
            #pragma unroll
            for (int j = 0; j < ACTN; j += 3) {
                h0 += fmaxf(u + W2act[(j    ) * 64 + t], 0.f);
                h1 += fmaxf(u + W2act[(j + 1) * 64 + t], 0.f);
                h2 += fmaxf(u + W2act[(j + 2) * 64 + t], 0.f);
            }
            hacc += (h0 + h1) + h2;
            cnt  += 21.f;
        } else {                                // single action (or none, id==-1)
            float ar = (js >= 0) ? W2act[js * 64 + t] : 0.f;
            hacc += fmaxf(u + ar, 0.f);
            cnt  += 1.f;
        }
    }
    sb[S_H + t] = hacc;
    __syncthreads();

    // ---- final: q = h @ fc3_w + cnt*fc3_b ----
    if (t < ACTN) {
        float q0 = cnt * f3b[t], q1 = 0.f;
        const float4* hp = (const float4*)&sb[S_H];
        #pragma unroll 4
        for (int hq = 0; hq < 16; ++hq) {
            float4 h = hp[hq];
            float4 w;
            if constexpr (TW) w = wp[F3P + hq * 21 + t];
            else w = make_float4(f3w[(4*hq+0)*21+t], f3w[(4*hq+1)*21+t],
                                 f3w[(4*hq+2)*21+t], f3w[(4*hq+3)*21+t]);
            q0 = fmaf(h.x, w.x, q0);
            q1 = fmaf(h.y, w.y, q1);
            q0 = fmaf(h.z, w.z, q0);
            q1 = fmaf(h.w, w.w, q1);
        }
        out[b * 21 + t] = q0 + q1;
    }
}

extern "C" void kernel_launch(void* const* d_in, const int* in_sizes, int n_in,
                              void* d_out, int out_size, void* d_ws, size_t ws_size,
                              hipStream_t stream) {
    const float* obs = (const float*)d_in[0];
    const float* c1w = (const float*)d_in[1];
    const float* c1b = (const float*)d_in[2];
    const float* c2w = (const float*)d_in[3];
    const float* c2b = (const float*)d_in[4];
    const float* f1w = (const float*)d_in[5];
    const float* f1b = (const float*)d_in[6];
    const float* f2w = (const float*)d_in[7];
    const float* f2b = (const float*)d_in[8];
    const float* f3w = (const float*)d_in[9];
    const float* f3b = (const float*)d_in[10];
    float* ws = (float*)d_ws;
    float* o  = (float*)d_out;

    const bool tw = ws_size >= (size_t)WS_F4 * 4 * sizeof(float);
    if (tw) {
        repack_k<<<(WS_F4 + 255) / 256, 256, 0, stream>>>(c1w, c2w, f1w, f2w, f3w, (float4*)ws);
        fused_k<true><<<4096, 64, 0, stream>>>(obs, c1w, c1b, c2w, c2b, f1w, f1b,
                                               f2w, f2b, f3w, f3b, ws, o);
    } else {
        fused_k<false><<<4096, 64, 0, stream>>>(obs, c1w, c1b, c2w, c2b, f1w, f1b,
                                                f2w, f2b, f3w, f3b, ws, o);
    }
}

// Round 8
// 34.791 us; speedup vs baseline: 1.3637x; 1.1921x over previous
//
#include <hip/hip_runtime.h>

typedef __attribute__((ext_vector_type(8))) short bf16x8;
typedef __attribute__((ext_vector_type(4))) float f32x4;

constexpr int OBS  = 682;
constexpr int ACTN = 21;
constexpr int MB   = 16;          // rows per block

// ---- ws (ushort units): bf16 B-fragments, 512 ushorts per 16x16x32 frag ----
constexpr int WS_C1U  = 0;        // conv1: K=64(pad from 45), N=32 -> 2s x 2nt = 4 frags
constexpr int WS_C2U  = 2048;     // conv2: K=288, N=32 -> 9s x 2nt = 18 frags
constexpr int WS_F1U  = 11264;    // fc1:   K=192, N=64 -> 6s x 4nt = 24 frags
constexpr int WS_TOTU = 23552;    // 46 frags

__device__ __forceinline__ unsigned short f2bf(float x) {
    unsigned u = __float_as_uint(x);
    return (unsigned short)((u + 0x7FFFu + ((u >> 16) & 1u)) >> 16);
}

__global__ void repack_b(const float* __restrict__ c1w, const float* __restrict__ c2w,
                         const float* __restrict__ f1w, unsigned short* __restrict__ wsu) {
    int i = blockIdx.x * 256 + threadIdx.x;
    if (i >= WS_TOTU) return;
    int frag = i >> 9, within = i & 511;
    int l = within >> 3, j = within & 7;
    int q = l >> 4, l15 = l & 15;
    float v = 0.f;
    if (frag < 4) {                          // conv1 B[k<45 pad64][oc32]
        int s = frag >> 1, nt = frag & 1;
        int k = 32 * s + 8 * q + j, n = 16 * nt + l15;
        if (k < 45) v = c1w[n * 45 + k];
    } else if (frag < 22) {                  // conv2 B[288][32]
        int f = frag - 4, s = f >> 1, nt = f & 1;
        int k = 32 * s + 8 * q + j, n = 16 * nt + l15;
        v = c2w[n * 288 + k];
    } else {                                 // fc1 B[192][64]
        int f = frag - 22, s = f >> 2, nt = f & 3;
        int k = 32 * s + 8 * q + j, n = 16 * nt + l15;
        v = f1w[k * 64 + n];
    }
    wsu[i] = f2bf(v);
}

__global__ __launch_bounds__(512, 1) void mfma_k(
    const float* __restrict__ obs,
    const float* __restrict__ c1b, const float* __restrict__ c2b,
    const float* __restrict__ f1b, const float* __restrict__ f2w,
    const float* __restrict__ f2b, const float* __restrict__ f3w,
    const float* __restrict__ f3b,
    const unsigned short* __restrict__ wsu,
    float* __restrict__ out)
{
    const int t = threadIdx.x;
    const int w = t >> 6, l = t & 63;
    const int q = l >> 4, l15 = l & 15;
    const int b16 = blockIdx.x * MB;

    __shared__ __align__(16) unsigned short sv[MB * 280];   // view bf16 [row][c*56+r*8+col]
    __shared__ __align__(16) unsigned short uA[96 * 296];   // A1[320][64] then A2[96][296]
    __shared__ __align__(16) unsigned short sc1[MB * 640];  // bf16 [row][ic*20+pos]
    __shared__ __align__(16) unsigned short sc2[MB * 200];  // bf16 [row][oc*6+pos pad]
    __shared__ __align__(16) float sfeat32[MB * 32];        // fp32 feat
    __shared__ __align__(16) float sx32[MB * 64];           // fp32 x (relu fc1)
    __shared__ __align__(16) float sbase[MB * 64];
    __shared__ __align__(16) float sh32[MB * 64];
    __shared__ __align__(16) float sW[2624];                // W2id[20][64] | W2act[21][64]
    __shared__ __align__(16) float sW2[6144];               // W2x[64][64] | W2f[32][64]
    __shared__ __align__(16) float sf3[1344];               // fc3 [64][21]
    __shared__ __align__(16) float sbias[224];              // c1b|c2b|f1b|f2b|f3b
    __shared__ float scnt[MB];
    __shared__ int smeta[MB * 20];
    __shared__ unsigned short tap1[48], tap2[288], mb2[96];

    // ================= phase 0: staging + tables + meta =================
    for (int e = t; e < MB * 210; e += 512) {               // view -> bf16 padded
        int row = e / 210, i2 = e - row * 210;
        int c = i2 / 42, rem = i2 - c * 42;
        int r3 = rem / 6, col = rem - r3 * 6;
        sv[row * 280 + c * 56 + r3 * 8 + col] = f2bf(obs[(long)(b16 + row) * OBS + i2]);
    }
    {                                                        // feat -> fp32
        int row = t >> 5, j = t & 31;
        sfeat32[row * 32 + j] = obs[(long)(b16 + row) * OBS + 210 + j];
    }
    {                                                        // fp32 weight staging (f4)
        const float4* src2 = (const float4*)f2w;             // W2x|W2f = first 6144 floats
        float4* d2 = (float4*)sW2;
        #pragma unroll
        for (int kk = 0; kk < 3; ++kk) d2[t + kk * 512] = src2[t + kk * 512];
        const float4* srcw = (const float4*)(f2w + 96 * 64); // W2id|W2act 2624 floats
        float4* dw = (float4*)sW;
        if (t < 512) { dw[t] = srcw[t]; if (t < 144) dw[512 + t] = srcw[512 + t]; }
        const float4* src3 = (const float4*)f3w;             // 1344 floats
        float4* d3 = (float4*)sf3;
        if (t < 336) d3[t] = src3[t];
    }
    if (t < 224) {
        float v = 0.f;
        if (t < 32) v = c1b[t];
        else if (t < 64) v = c2b[t - 32];
        else if (t < 128) v = f1b[t - 64];
        else if (t < 192) v = f2b[t - 128];
        else if (t < 213) v = f3b[t - 192];
        sbias[t] = v;
    }
    if (t < 48) {
        int c = t / 9, rem = t - c * 9;
        tap1[t] = (unsigned short)(c * 56 + (rem / 3) * 8 + (rem % 3));
    }
    if (t < 288) {
        int ic = t / 9, rem = t - ic * 9;
        tap2[t] = (unsigned short)(ic * 20 + (rem / 3) * 4 + (rem % 3));
    }
    if (t < 96) {
        int row = t / 6, pos = t - row * 6;
        mb2[t] = (unsigned short)(row * 640 + (pos >> 1) * 4 + (pos & 1));
    }
    if (t < 320) {                                           // meta (exact fp32 from global)
        int row = t / 20, a = t - row * 20;
        const float* nb = obs + (long)(b16 + row) * OBS + 242 + a * 22;
        int id = (int)nb[0];
        int js = -1;
        #pragma unroll
        for (int j = 0; j < ACTN; ++j) {
            float av = nb[1 + j];
            js = (av != 0.f && js < 0) ? j : js;
        }
        int mode = (id < -1) ? 0 : ((id >= 0 && js < 0) ? 1 : 2);
        smeta[t] = ((id + 2) << 8) | (mode << 5) | (js + 1);
    }
    __syncthreads();

    // ================= phase 1: A1[320][64], zero-padded k>=45 =================
    if (t < 320) {
        int row = t / 20, pos = t - row * 20;
        int base = row * 280 + (pos >> 2) * 8 + (pos & 3);
        #pragma unroll
        for (int k = 0; k < 64; ++k)
            uA[t * 64 + k] = (k < 45) ? sv[base + tap1[k]] : (unsigned short)0;
    }
    __syncthreads();

    // ================= phase 2: conv1 MFMA (M320 N32 K64pad) =================
    {
        #pragma unroll
        for (int u = 0; u < 5; ++u) {
            int p = w + 8 * u;                  // 0..39 = mt*2+nt
            int mt = p >> 1, nt = p & 1;
            f32x4 acc = {0.f, 0.f, 0.f, 0.f};
            #pragma unroll
            for (int s = 0; s < 2; ++s) {
                bf16x8 a = *(const bf16x8*)&uA[(mt * 16 + l15) * 64 + 32 * s + 8 * q];
                bf16x8 bb = *(const bf16x8*)&wsu[WS_C1U + (s * 2 + nt) * 512 + l * 8];
                acc = __builtin_amdgcn_mfma_f32_16x16x32_bf16(a, bb, acc, 0, 0, 0);
            }
            int oc = nt * 16 + l15;
            float bias = sbias[oc];
            #pragma unroll
            for (int r = 0; r < 4; ++r) {
                int m = mt * 16 + 4 * q + r;
                int row = m / 20, pos = m - row * 20;
                sc1[row * 640 + oc * 20 + pos] = f2bf(fmaxf(acc[r] + bias, 0.f));
            }
        }
    }
    __syncthreads();

    // ================= phase 3: im2col A2[96][296] =================
    for (int e = t; e < 96 * 288; e += 512) {
        int m = e / 288, k = e - m * 288;
        uA[m * 296 + k] = sc1[mb2[m] + tap2[k]];
    }
    __syncthreads();

    // ================= phase 4: conv2 MFMA (M96 N32 K288) =================
    {
        #pragma unroll
        for (int u = 0; u < 2; ++u) {
            int p = w + 8 * u;
            if (p < 12) {
                int mt = p >> 1, nt = p & 1;
                f32x4 acc = {0.f, 0.f, 0.f, 0.f};
                #pragma unroll
                for (int s = 0; s < 9; ++s) {
                    bf16x8 a = *(const bf16x8*)&uA[(mt * 16 + l15) * 296 + 32 * s + 8 * q];
                    bf16x8 bb = *(const bf16x8*)&wsu[WS_C2U + (s * 2 + nt) * 512 + l * 8];
                    acc = __builtin_amdgcn_mfma_f32_16x16x32_bf16(a, bb, acc, 0, 0, 0);
                }
                int oc = nt * 16 + l15;
                float bias = sbias[32 + oc];
                #pragma unroll
                for (int r = 0; r < 4; ++r) {
                    int m = mt * 16 + 4 * q + r;
                    int row = m / 6, pos = m - row * 6;
                    sc2[row * 200 + oc * 6 + pos] = f2bf(fmaxf(acc[r] + bias, 0.f));
                }
            }
        }
    }
    __syncthreads();

    // ================= phase 5: fc1 MFMA (M16 N64 K192) -> fp32 x =================
    if (w < 4) {
        int nt = w;
        f32x4 acc = {0.f, 0.f, 0.f, 0.f};
        #pragma unroll
        for (int s = 0; s < 6; ++s) {
            bf16x8 a = *(const bf16x8*)&sc2[l15 * 200 + 32 * s + 8 * q];
            bf16x8 bb = *(const bf16x8*)&wsu[WS_F1U + (s * 4 + nt) * 512 + l * 8];
            acc = __builtin_amdgcn_mfma_f32_16x16x32_bf16(a, bb, acc, 0, 0, 0);
        }
        int h = nt * 16 + l15;
        float bias = sbias[64 + h];
        #pragma unroll
        for (int r = 0; r < 4; ++r) {
            int row = 4 * q + r;
            sx32[row * 64 + h] = fmaxf(acc[r] + bias, 0.f);
        }
    }
    __syncthreads();

    // ================= phase 6: base fp32 VALU (2 rows/wave) =================
    {
        int r0 = 2 * w, r1 = 2 * w + 1;
        float a0 = sbias[128 + l], a1 = a0;
        #pragma unroll 4
        for (int k = 0; k < 64; ++k) {
            float wv = sW2[k * 64 + l];
            a0 = fmaf(sx32[r0 * 64 + k], wv, a0);
            a1 = fmaf(sx32[r1 * 64 + k], wv, a1);
        }
        #pragma unroll 4
        for (int k = 0; k < 32; ++k) {
            float wv = sW2[(64 + k) * 64 + l];
            a0 = fmaf(sfeat32[r0 * 32 + k], wv, a0);
            a1 = fmaf(sfeat32[r1 * 32 + k], wv, a1);
        }
        sbase[r0 * 64 + l] = a0;
        sbase[r1 * 64 + l] = a1;
    }
    __syncthreads();

    // ================= phase 7: agents fp32 VALU (exact logic) =================
    {
        #pragma unroll
        for (int rr = 0; rr < 2; ++rr) {
            int row = 2 * w + rr;
            float base_l = sbase[row * 64 + l];
            float hacc = 0.f, cnt = 0.f;
            for (int a = 0; a < 20; ++a) {
                int m = smeta[row * 20 + a];
                int mode = (m >> 5) & 3;
                if (mode == 0) continue;
                int id = (m >> 8) - 2;
                int js = (m & 31) - 1;
                float u = base_l + ((id >= 0) ? sW[id * 64 + l] : 0.f);
                if (mode == 1) {                 // expand: sum_j relu(u + W2act[j])
                    float h0 = 0.f, h1 = 0.f, h2 = 0.f;
                    #pragma unroll
                    for (int j = 0; j < ACTN; j += 3) {
                        h0 += fmaxf(u + sW[1280 + (j    ) * 64 + l], 0.f);
                        h1 += fmaxf(u + sW[1280 + (j + 1) * 64 + l], 0.f);
                        h2 += fmaxf(u + sW[1280 + (j + 2) * 64 + l], 0.f);
                    }
                    hacc += (h0 + h1) + h2;
                    cnt  += 21.f;
                } else {
                    float ar = (js >= 0) ? sW[1280 + js * 64 + l] : 0.f;
                    hacc += fmaxf(u + ar, 0.f);
                    cnt  += 1.f;
                }
            }
            sh32[row * 64 + l] = hacc;
            if (l == 0) scnt[row] = cnt;
        }
    }
    __syncthreads();

    // ================= phase 8: fc3 fp32 VALU + store =================
    if (l < ACTN) {
        int r0 = 2 * w, r1 = 2 * w + 1;
        float fb = sbias[192 + l];
        float q0 = scnt[r0] * fb, q1 = scnt[r1] * fb;
        #pragma unroll 4
        for (int h = 0; h < 64; ++h) {
            float wf = sf3[h * 21 + l];
            q0 = fmaf(sh32[r0 * 64 + h], wf, q0);
            q1 = fmaf(sh32[r1 * 64 + h], wf, q1);
        }
        out[(long)(b16 + r0) * 21 + l] = q0;
        out[(long)(b16 + r1) * 21 + l] = q1;
    }
}

// ================= fallback: R6 structure, raw weights (no ws) =================
__device__ __forceinline__ float comp4(float4 v, int i) {
    return (i == 0) ? v.x : (i == 1) ? v.y : (i == 2) ? v.z : v.w;
}

constexpr int S_V = 0, S_OBS = 280, S_C1 = 968, S_PART = 1608, S_C2 = 1992,
              S_X = 2184, S_H = 2248, S_TOT = 2312;

__global__ __launch_bounds__(64, 4) void fallback_k(
    const float* __restrict__ obs,
    const float* __restrict__ c1w, const float* __restrict__ c1b,
    const float* __restrict__ c2w, const float* __restrict__ c2b,
    const float* __restrict__ f1w, const float* __restrict__ f1b,
    const float* __restrict__ f2w, const float* __restrict__ f2b,
    const float* __restrict__ f3w, const float* __restrict__ f3b,
    float* __restrict__ out)
{
    const int b = blockIdx.x, t = threadIdx.x;
    __shared__ __align__(16) float sb[S_TOT];
    __shared__ int s_meta[20];
    {
        const float* orow = obs + (long)b * OBS;
        #pragma unroll
        for (int k = 0; k < 4; ++k) {
            int i = t + k * 64;
            if (i < 210) {
                int c = i / 42, rem = i - 42 * c, r = rem / 6, col = rem - 6 * r;
                sb[S_V + c * 56 + r * 8 + col] = orow[i];
            }
        }
        #pragma unroll
        for (int k = 0; k < 8; ++k) {
            int i = 210 + t + k * 64;
            if (i < OBS) sb[S_OBS + i] = orow[i];
        }
    }
    __syncthreads();
    if (t < 20) {
        const float* nb = &sb[S_OBS + 242 + t * 22];
        int id = (int)nb[0], js = -1;
        #pragma unroll
        for (int j = 0; j < ACTN; ++j) {
            float av = nb[1 + j];
            js = (av != 0.f && js < 0) ? j : js;
        }
        int mode = (id < -1) ? 0 : ((id >= 0 && js < 0) ? 1 : 2);
        s_meta[t] = ((id + 2) << 8) | (mode << 5) | (js + 1);
    }
    {
        const int oc = t & 31, s = t >> 5;
        float acc[12];
        #pragma unroll
        for (int i = 0; i < 12; ++i) acc[i] = 0.f;
        #pragma unroll
        for (int c = 0; c < 5; ++c) {
            float wv[9];
            #pragma unroll
            for (int k = 0; k < 9; ++k) wv[k] = c1w[oc * 45 + c * 9 + k];
            #pragma unroll
            for (int rr = 0; rr < 5; ++rr) {
                const float* rowp = &sb[S_V + c * 56 + (2 * s + rr) * 8];
                float4 v0 = *(const float4*)rowp;
                float2 v1 = *(const float2*)(rowp + 4);
                float c0 = v0.x, c1 = v0.y, c2 = v0.z, c3 = v0.w, c4 = v1.x, c5 = v1.y;
                #pragma unroll
                for (int kh = 0; kh < 3; ++kh) {
                    int ohl = rr - kh;
                    if (ohl < 0 || ohl > 2) continue;
                    acc[ohl*4+0] = fmaf(c0, wv[kh*3+0], acc[ohl*4+0]);
                    acc[ohl*4+0] = fmaf(c1, wv[kh*3+1], acc[ohl*4+0]);
                    acc[ohl*4+0] = fmaf(c2, wv[kh*3+2], acc[ohl*4+0]);
                    acc[ohl*4+1] = fmaf(c1, wv[kh*3+0], acc[ohl*4+1]);
                    acc[ohl*4+1] = fmaf(c2, wv[kh*3+1], acc[ohl*4+1]);
                    acc[ohl*4+1] = fmaf(c3, wv[kh*3+2], acc[ohl*4+1]);
                    acc[ohl*4+2] = fmaf(c2, wv[kh*3+0], acc[ohl*4+2]);
                    acc[ohl*4+2] = fmaf(c3, wv[kh*3+1], acc[ohl*4+2]);
                    acc[ohl*4+2] = fmaf(c4, wv[kh*3+2], acc[ohl*4+2]);
                    acc[ohl*4+3] = fmaf(c3, wv[kh*3+0], acc[ohl*4+3]);
                    acc[ohl*4+3] = fmaf(c4, wv[kh*3+1], acc[ohl*4+3]);
                    acc[ohl*4+3] = fmaf(c5, wv[kh*3+2], acc[ohl*4+3]);
                }
            }
        }
        float bias = c1b[oc];
        #pragma unroll
        for (int ohl = 0; ohl < 3; ++ohl) {
            int oh = 2 * s + ohl;
            float4 o4 = make_float4(fmaxf(acc[ohl*4+0] + bias, 0.f), fmaxf(acc[ohl*4+1] + bias, 0.f),
                                    fmaxf(acc[ohl*4+2] + bias, 0.f), fmaxf(acc[ohl*4+3] + bias, 0.f));
            *(float4*)&sb[S_C1 + oc * 20 + oh * 4] = o4;
        }
    }
    __syncthreads();
    {
        const int oc = t & 31, half = t >> 5;
        float a0=0,a1=0,a2=0,a3=0,a4=0,a5=0;
        #pragma unroll 4
        for (int icc = 0; icc < 16; ++icc) {
            const int ic = half * 16 + icc;
            const float4* rp = (const float4*)&sb[S_C1 + ic * 20];
            float4 r0 = rp[0], r1 = rp[1], r2 = rp[2], r3 = rp[3], r4 = rp[4];
            float wv[9];
            #pragma unroll
            for (int k = 0; k < 9; ++k) wv[k] = c2w[oc * 288 + ic * 9 + k];
            #pragma unroll
            for (int kh = 0; kh < 3; ++kh) {
                float4 ra = (kh == 0) ? r0 : (kh == 1) ? r1 : r2;
                float4 rb = (kh == 0) ? r1 : (kh == 1) ? r2 : r3;
                float4 rc = (kh == 0) ? r2 : (kh == 1) ? r3 : r4;
                #pragma unroll
                for (int kw = 0; kw < 3; ++kw) {
                    float ww = wv[kh * 3 + kw];
                    a0 = fmaf(comp4(ra, kw),     ww, a0);
                    a1 = fmaf(comp4(ra, kw + 1), ww, a1);
                    a2 = fmaf(comp4(rb, kw),     ww, a2);
                    a3 = fmaf(comp4(rb, kw + 1), ww, a3);
                    a4 = fmaf(comp4(rc, kw),     ww, a4);
                    a5 = fmaf(comp4(rc, kw + 1), ww, a5);
                }
            }
        }
        float* pp = &sb[S_PART + (half * 32 + oc) * 6];
        pp[0]=a0; pp[1]=a1; pp[2]=a2; pp[3]=a3; pp[4]=a4; pp[5]=a5;
    }
    __syncthreads();
    if (t < 32) {
        float bias = c2b[t];
        #pragma unroll
        for (int p = 0; p < 6; ++p)
            sb[S_C2 + t * 6 + p] = fmaxf(sb[S_PART + t * 6 + p] + sb[S_PART + (32 + t) * 6 + p] + bias, 0.f);
    }
    __syncthreads();
    {
        float a0 = f1b[t], a1 = 0.f;
        const float4* xp = (const float4*)&sb[S_C2];
        #pragma unroll 4
        for (int kq = 0; kq < 48; ++kq) {
            float4 x = xp[kq];
            a0 = fmaf(x.x, f1w[(4*kq+0)*64+t], a0);
            a1 = fmaf(x.y, f1w[(4*kq+1)*64+t], a1);
            a0 = fmaf(x.z, f1w[(4*kq+2)*64+t], a0);
            a1 = fmaf(x.w, f1w[(4*kq+3)*64+t], a1);
        }
        sb[S_X + t] = fmaxf(a0 + a1, 0.f);
    }
    __syncthreads();
    float base_t;
    {
        float a0 = f2b[t], a1 = 0.f;
        const float4* xp = (const float4*)&sb[S_X];
        #pragma unroll 4
        for (int kq = 0; kq < 16; ++kq) {
            float4 x = xp[kq];
            a0 = fmaf(x.x, f2w[(4*kq+0)*64+t], a0);
            a1 = fmaf(x.y, f2w[(4*kq+1)*64+t], a1);
            a0 = fmaf(x.z, f2w[(4*kq+2)*64+t], a0);
            a1 = fmaf(x.w, f2w[(4*kq+3)*64+t], a1);
        }
        const float2* fp = (const float2*)&sb[S_OBS + 210];
        #pragma unroll 4
        for (int i2 = 0; i2 < 16; ++i2) {
            float2 v = fp[i2];
            a0 = fmaf(v.x, f2w[(64 + i2*2+0)*64+t], a0);
            a1 = fmaf(v.y, f2w[(64 + i2*2+1)*64+t], a1);
        }
        base_t = a0 + a1;
    }
    const float* W2id = f2w + 96 * 64;
    const float* W2act = f2w + 116 * 64;
    float hacc = 0.f, cnt = 0.f;
    for (int a = 0; a < 20; ++a) {
        int m = s_meta[a];
        int mode = (m >> 5) & 3;
        if (mode == 0) continue;
        int id = (m >> 8) - 2, js = (m & 31) - 1;
        float u = base_t + ((id >= 0) ? W2id[id * 64 + t] : 0.f);
        if (mode == 1) {
            float h0=0,h1=0,h2=0;
            #pragma unroll
            for (int j = 0; j < ACTN; j += 3) {
                h0 += fmaxf(u + W2act[(j    )*64+t], 0.f);
                h1 += fmaxf(u + W2act[(j + 1)*64+t], 0.f);
                h2 += fmaxf(u + W2act[(j + 2)*64+t], 0.f);
            }
            hacc += (h0 + h1) + h2; cnt += 21.f;
        } else {
            float ar = (js >= 0) ? W2act[js * 64 + t] : 0.f;
            hacc += fmaxf(u + ar, 0.f); cnt += 1.f;
        }
    }
    sb[S_H + t] = hacc;
    __syncthreads();
    if (t < ACTN) {
        float q0 = cnt * f3b[t], q1 = 0.f;
        const float4* hp = (const float4*)&sb[S_H];
        #pragma unroll 4
        for (int h4 = 0; h4 < 16; ++h4) {
            float4 v = hp[h4];
            q0 = fmaf(v.x, f3w[(h4*4+0)*21+t], q0);
            q1 = fmaf(v.y, f3w[(h4*4+1)*21+t], q1);
            q0 = fmaf(v.z, f3w[(h4*4+2)*21+t], q0);
            q1 = fmaf(v.w, f3w[(h4*4+3)*21+t], q1);
        }
        out[b * 21 + t] = q0 + q1;
    }
}

extern "C" void kernel_launch(void* const* d_in, const int* in_sizes, int n_in,
                              void* d_out, int out_size, void* d_ws, size_t ws_size,
                              hipStream_t stream) {
    const float* obs = (const float*)d_in[0];
    const float* c1w = (const float*)d_in[1];
    const float* c1b = (const float*)d_in[2];
    const float* c2w = (const float*)d_in[3];
    const float* c2b = (const float*)d_in[4];
    const float* f1w = (const float*)d_in[5];
    const float* f1b = (const float*)d_in[6];
    const float* f2w = (const float*)d_in[7];
    const float* f2b = (const float*)d_in[8];
    const float* f3w = (const float*)d_in[9];
    const float* f3b = (const float*)d_in[10];
    float* o = (float*)d_out;
    const int B = in_sizes[0] / OBS;

    if (ws_size >= (size_t)WS_TOTU * 2 && (B % MB) == 0) {
        unsigned short* wsu = (unsigned short*)d_ws;
        repack_b<<<(WS_TOTU + 255) / 256, 256, 0, stream>>>(c1w, c2w, f1w, wsu);
        mfma_k<<<B / MB, 512, 0, stream>>>(obs, c1b, c2b, f1b, f2w, f2b, f3w, f3b, wsu, o);
    } else {
        fallback_k<<<B, 64, 0, stream>>>(obs, c1w, c1b, c2w, c2b, f1w, f1b,
                                         f2w, f2b, f3w, f3b, o);
    }
}

// Round 9
// 29.996 us; speedup vs baseline: 1.5817x; 1.1599x over previous
//
#include <hip/hip_runtime.h>

typedef __attribute__((ext_vector_type(8))) short bf16x8;
typedef __attribute__((ext_vector_type(4))) float f32x4;

constexpr int OBS  = 682;
constexpr int ACTN = 21;
constexpr int MB   = 8;           // rows per block

// ---- ws (ushort units): bf16 B-fragments, 512 ushorts per 16x16x32 frag ----
constexpr int WS_C1U  = 0;        // conv1: K=64(pad from 45), N=32 -> 2s x 2nt = 4 frags
constexpr int WS_C2U  = 2048;     // conv2: K=288, N=32 -> 9s x 2nt = 18 frags
constexpr int WS_F1U  = 11264;    // fc1:   K=192, N=64 -> 6s x 4nt = 24 frags
constexpr int WS_TOTU = 23552;    // 46 frags

__device__ __forceinline__ unsigned short f2bf(float x) {
    unsigned u = __float_as_uint(x);
    return (unsigned short)((u + 0x7FFFu + ((u >> 16) & 1u)) >> 16);
}

__global__ void repack_b(const float* __restrict__ c1w, const float* __restrict__ c2w,
                         const float* __restrict__ f1w, unsigned short* __restrict__ wsu) {
    int i = blockIdx.x * 256 + threadIdx.x;
    if (i >= WS_TOTU) return;
    int frag = i >> 9, within = i & 511;
    int l = within >> 3, j = within & 7;
    int q = l >> 4, l15 = l & 15;
    float v = 0.f;
    if (frag < 4) {                          // conv1 B[k<45 pad64][oc32]
        int s = frag >> 1, nt = frag & 1;
        int k = 32 * s + 8 * q + j, n = 16 * nt + l15;
        if (k < 45) v = c1w[n * 45 + k];
    } else if (frag < 22) {                  // conv2 B[288][32]
        int f = frag - 4, s = f >> 1, nt = f & 1;
        int k = 32 * s + 8 * q + j, n = 16 * nt + l15;
        v = c2w[n * 288 + k];
    } else {                                 // fc1 B[192][64]
        int f = frag - 22, s = f >> 2, nt = f & 3;
        int k = 32 * s + 8 * q + j, n = 16 * nt + l15;
        v = f1w[k * 64 + n];
    }
    wsu[i] = f2bf(v);
}

__global__ __launch_bounds__(512, 4) void mfma_k(
    const float* __restrict__ obs,
    const float* __restrict__ c1b, const float* __restrict__ c2b,
    const float* __restrict__ f1b, const float* __restrict__ f2w,
    const float* __restrict__ f2b, const float* __restrict__ f3w,
    const float* __restrict__ f3b,
    const unsigned short* __restrict__ wsu,
    float* __restrict__ out)
{
    const int t = threadIdx.x;
    const int w = t >> 6, l = t & 63;
    const int q = l >> 4, l15 = l & 15;
    const int b8 = blockIdx.x * MB;

    __shared__ __align__(16) unsigned short sv[MB * 280];   // view bf16 [row][c*56+r*8+col]
    __shared__ __align__(16) unsigned short uA[7680];       // A1[160][48] then A2[48][160]
    __shared__ __align__(16) unsigned short sc1[MB * 640];  // bf16 [row][ic*20+pos]; sc2 overlays
    __shared__ __align__(16) float sfeat32[MB * 32];
    __shared__ __align__(16) float sx32[MB * 64];           // fp32 x; sh32 overlays
    __shared__ __align__(16) float sW2[6144];               // W2x[64][64] | W2f[32][64]
    __shared__ __align__(16) float sW[2624];                // W2id[20][64] | W2act[21][64]
    __shared__ __align__(16) float sf3[1344];               // fc3 [64][21]
    __shared__ __align__(16) float sbias[224];              // c1b|c2b|f1b|f2b|f3b
    __shared__ int smeta[MB * 20];
    __shared__ unsigned short tap1[48], tap2[288], mb2[MB * 6];

    unsigned short* sc2 = sc1;        // overlay: sc1 dead after conv2 staging
    float* sh32 = sx32;               // overlay: sx32 dead after base (wave-row-local)

    // ================= phase 0: staging + tables + meta =================
    for (int e = t; e < MB * 210; e += 512) {               // view -> bf16 padded
        int row = e / 210, i2 = e - row * 210;
        int c = i2 / 42, rem = i2 - c * 42;
        int r3 = rem / 6, col = rem - r3 * 6;
        sv[row * 280 + c * 56 + r3 * 8 + col] = f2bf(obs[(long)(b8 + row) * OBS + i2]);
    }
    if (t < MB * 32) {                                       // feat -> fp32
        int row = t >> 5, j = t & 31;
        sfeat32[t] = obs[(long)(b8 + row) * OBS + 210 + j];
    }
    {                                                        // fp32 weight staging (f4)
        const float4* src2 = (const float4*)f2w;             // W2x|W2f = first 6144 floats
        float4* d2 = (float4*)sW2;
        #pragma unroll
        for (int kk = 0; kk < 3; ++kk) d2[t + kk * 512] = src2[t + kk * 512];
        const float4* srcw = (const float4*)(f2w + 96 * 64); // W2id|W2act 2624 floats
        float4* dw = (float4*)sW;
        if (t < 512) { dw[t] = srcw[t]; if (t < 144) dw[512 + t] = srcw[512 + t]; }
        const float4* src3 = (const float4*)f3w;             // 1344 floats
        float4* d3 = (float4*)sf3;
        if (t < 336) d3[t] = src3[t];
    }
    if (t < 224) {
        float v = 0.f;
        if (t < 32) v = c1b[t];
        else if (t < 64) v = c2b[t - 32];
        else if (t < 128) v = f1b[t - 64];
        else if (t < 192) v = f2b[t - 128];
        else if (t < 213) v = f3b[t - 192];
        sbias[t] = v;
    }
    if (t < 48) {
        int c = t / 9, rem = t - c * 9;
        tap1[t] = (unsigned short)(c * 56 + (rem / 3) * 8 + (rem % 3));
    }
    if (t < 288) {
        int ic = t / 9, rem = t - ic * 9;
        tap2[t] = (unsigned short)(ic * 20 + (rem / 3) * 4 + (rem % 3));
    }
    if (t < MB * 6) {
        int row = t / 6, pos = t - row * 6;
        mb2[t] = (unsigned short)(row * 640 + (pos >> 1) * 4 + (pos & 1));
    }
    if (t < MB * 20) {                                       // meta (exact fp32 from global)
        int row = t / 20, a = t - row * 20;
        const float* nb = obs + (long)(b8 + row) * OBS + 242 + a * 22;
        int id = (int)nb[0];
        int js = -1;
        #pragma unroll
        for (int j = 0; j < ACTN; ++j) {
            float av = nb[1 + j];
            js = (av != 0.f && js < 0) ? j : js;
        }
        int mode = (id < -1) ? 0 : ((id >= 0 && js < 0) ? 1 : 2);
        smeta[t] = ((id + 2) << 8) | (mode << 5) | (js + 1);
    }
    __syncthreads();

    // ================= phase 1: A1[160][48] (k>=45 zero) =================
    for (int e = t; e < 160 * 45; e += 512) {
        int rowm = e / 45, k = e - rowm * 45;
        int brow = rowm / 20, pos = rowm - brow * 20;
        int base = brow * 280 + (pos >> 2) * 8 + (pos & 3);
        uA[rowm * 48 + k] = sv[base + tap1[k]];
    }
    if (t < 480) {
        int rowm = t / 3, k = 45 + (t % 3);
        uA[rowm * 48 + k] = 0;
    }
    __syncthreads();

    // ================= phase 2: conv1 MFMA (M160 N32, 20 tiles) =================
    {
        #pragma unroll
        for (int u = 0; u < 3; ++u) {
            int p = w + 8 * u;                  // tile = mt*2+nt
            if (p < 20) {
                int mt = p >> 1, nt = p & 1;
                f32x4 acc = {0.f, 0.f, 0.f, 0.f};
                {   // s = 0: k 0..31
                    bf16x8 a = *(const bf16x8*)&uA[(mt * 16 + l15) * 48 + 8 * q];
                    bf16x8 bb = *(const bf16x8*)&wsu[WS_C1U + (0 + nt) * 512 + l * 8];
                    acc = __builtin_amdgcn_mfma_f32_16x16x32_bf16(a, bb, acc, 0, 0, 0);
                }
                {   // s = 1: k 32..63 ; q>=2 (k>=48) -> register zero (B is zero too)
                    bf16x8 a = {0, 0, 0, 0, 0, 0, 0, 0};
                    if (q < 2) a = *(const bf16x8*)&uA[(mt * 16 + l15) * 48 + 32 + 8 * q];
                    bf16x8 bb = *(const bf16x8*)&wsu[WS_C1U + (2 + nt) * 512 + l * 8];
                    acc = __builtin_amdgcn_mfma_f32_16x16x32_bf16(a, bb, acc, 0, 0, 0);
                }
                int oc = nt * 16 + l15;
                float bias = sbias[oc];
                #pragma unroll
                for (int r = 0; r < 4; ++r) {
                    int m = mt * 16 + 4 * q + r;
                    int row = m / 20, pos = m - row * 20;
                    sc1[row * 640 + oc * 20 + pos] = f2bf(fmaxf(acc[r] + bias, 0.f));
                }
            }
        }
    }
    __syncthreads();

    // ================= phase 3a: A2[48][160] stage a (k 0..159) =================
    for (int e = t; e < 48 * 160; e += 512) {
        int m = e / 160, k = e - m * 160;
        uA[m * 160 + k] = sc1[mb2[m] + tap2[k]];
    }
    __syncthreads();

    // ================= phase 4a: conv2 partial (s 0..4) =================
    f32x4 c2acc = {0.f, 0.f, 0.f, 0.f};
    const bool c2act = (w < 6);
    const int c2mt = w >> 1, c2nt = w & 1;
    if (c2act) {
        #pragma unroll
        for (int s = 0; s < 5; ++s) {
            bf16x8 a = *(const bf16x8*)&uA[(c2mt * 16 + l15) * 160 + 32 * s + 8 * q];
            bf16x8 bb = *(const bf16x8*)&wsu[WS_C2U + (s * 2 + c2nt) * 512 + l * 8];
            c2acc = __builtin_amdgcn_mfma_f32_16x16x32_bf16(a, bb, c2acc, 0, 0, 0);
        }
    }
    __syncthreads();

    // ================= phase 3b: A2 stage b (k 160..287 -> cols 0..127) =================
    for (int e = t; e < 48 * 128; e += 512) {
        int m = e >> 7, k2 = e & 127;
        uA[m * 160 + k2] = sc1[mb2[m] + tap2[160 + k2]];
    }
    __syncthreads();

    // ================= phase 4b: conv2 finish (s 5..8) + store sc2 =================
    if (c2act) {
        #pragma unroll
        for (int s = 5; s < 9; ++s) {
            bf16x8 a = *(const bf16x8*)&uA[(c2mt * 16 + l15) * 160 + 32 * (s - 5) + 8 * q];
            bf16x8 bb = *(const bf16x8*)&wsu[WS_C2U + (s * 2 + c2nt) * 512 + l * 8];
            c2acc = __builtin_amdgcn_mfma_f32_16x16x32_bf16(a, bb, c2acc, 0, 0, 0);
        }
        int oc = c2nt * 16 + l15;
        float bias = sbias[32 + oc];
        #pragma unroll
        for (int r = 0; r < 4; ++r) {
            int m = c2mt * 16 + 4 * q + r;
            int row = m / 6, pos = m - row * 6;
            sc2[row * 200 + oc * 6 + pos] = f2bf(fmaxf(c2acc[r] + bias, 0.f));
        }
    }
    __syncthreads();

    // ================= phase 5: fc1 MFMA (M16(8 valid) N64 K192) -> fp32 x ======
    if (w < 4) {
        int nt = w;
        f32x4 acc = {0.f, 0.f, 0.f, 0.f};
        #pragma unroll
        for (int s = 0; s < 6; ++s) {
            bf16x8 a = *(const bf16x8*)&sc2[l15 * 200 + 32 * s + 8 * q];
            bf16x8 bb = *(const bf16x8*)&wsu[WS_F1U + (s * 4 + nt) * 512 + l * 8];
            acc = __builtin_amdgcn_mfma_f32_16x16x32_bf16(a, bb, acc, 0, 0, 0);
        }
        int h = nt * 16 + l15;
        float bias = sbias[64 + h];
        #pragma unroll
        for (int r = 0; r < 4; ++r) {
            int row = 4 * q + r;
            if (row < MB) sx32[row * 64 + h] = fmaxf(acc[r] + bias, 0.f);
        }
    }
    __syncthreads();

    // ============ phases 6+7: base + agents, wave-row-local (row = w) ============
    float cnt;
    {
        const int row = w;
        // base (fp32, exact)
        float a0 = sbias[128 + l], a1 = 0.f;
        #pragma unroll 4
        for (int k = 0; k < 64; k += 2) {
            a0 = fmaf(sx32[row * 64 + k],     sW2[(k    ) * 64 + l], a0);
            a1 = fmaf(sx32[row * 64 + k + 1], sW2[(k + 1) * 64 + l], a1);
        }
        #pragma unroll 4
        for (int k = 0; k < 32; k += 2) {
            a0 = fmaf(sfeat32[row * 32 + k],     sW2[(64 + k    ) * 64 + l], a0);
            a1 = fmaf(sfeat32[row * 32 + k + 1], sW2[(64 + k + 1) * 64 + l], a1);
        }
        const float base_l = a0 + a1;
        // agents (fp32, exact logic)
        float hacc = 0.f;
        cnt = 0.f;
        for (int a = 0; a < 20; ++a) {
            int m = smeta[row * 20 + a];
            int mode = (m >> 5) & 3;
            if (mode == 0) continue;
            int id = (m >> 8) - 2;
            int js = (m & 31) - 1;
            float u = base_l + ((id >= 0) ? sW[id * 64 + l] : 0.f);
            if (mode == 1) {                 // expand: sum_j relu(u + W2act[j])
                float h0 = 0.f, h1 = 0.f, h2 = 0.f;
                #pragma unroll
                for (int j = 0; j < ACTN; j += 3) {
                    h0 += fmaxf(u + sW[1280 + (j    ) * 64 + l], 0.f);
                    h1 += fmaxf(u + sW[1280 + (j + 1) * 64 + l], 0.f);
                    h2 += fmaxf(u + sW[1280 + (j + 2) * 64 + l], 0.f);
                }
                hacc += (h0 + h1) + h2;
                cnt  += 21.f;
            } else {
                float ar = (js >= 0) ? sW[1280 + js * 64 + l] : 0.f;
                hacc += fmaxf(u + ar, 0.f);
                cnt  += 1.f;
            }
        }
        sh32[row * 64 + l] = hacc;           // overlay over sx32 (own row, read done)
    }
    __syncthreads();

    // ================= phase 8: fc3 fp32 + store (row = w) =================
    if (l < ACTN) {
        float qv = cnt * sbias[192 + l];     // cnt is wave-uniform, in register
        float q1 = 0.f;
        #pragma unroll 4
        for (int h = 0; h < 64; h += 2) {
            qv = fmaf(sh32[w * 64 + h],     sf3[(h    ) * 21 + l], qv);
            q1 = fmaf(sh32[w * 64 + h + 1], sf3[(h + 1) * 21 + l], q1);
        }
        out[(long)(b8 + w) * 21 + l] = qv + q1;
    }
}

// ================= fallback: R6 structure, raw weights (no ws) =================
__device__ __forceinline__ float comp4(float4 v, int i) {
    return (i == 0) ? v.x : (i == 1) ? v.y : (i == 2) ? v.z : v.w;
}

constexpr int S_V = 0, S_OBS = 280, S_C1 = 968, S_PART = 1608, S_C2 = 1992,
              S_X = 2184, S_H = 2248, S_TOT = 2312;

__global__ __launch_bounds__(64, 4) void fallback_k(
    const float* __restrict__ obs,
    const float* __restrict__ c1w, const float* __restrict__ c1b,
    const float* __restrict__ c2w, const float* __restrict__ c2b,
    const float* __restrict__ f1w, const float* __restrict__ f1b,
    const float* __restrict__ f2w, const float* __restrict__ f2b,
    const float* __restrict__ f3w, const float* __restrict__ f3b,
    float* __restrict__ out)
{
    const int b = blockIdx.x, t = threadIdx.x;
    __shared__ __align__(16) float sb[S_TOT];
    __shared__ int s_meta[20];
    {
        const float* orow = obs + (long)b * OBS;
        #pragma unroll
        for (int k = 0; k < 4; ++k) {
            int i = t + k * 64;
            if (i < 210) {
                int c = i / 42, rem = i - 42 * c, r = rem / 6, col = rem - 6 * r;
                sb[S_V + c * 56 + r * 8 + col] = orow[i];
            }
        }
        #pragma unroll
        for (int k = 0; k < 8; ++k) {
            int i = 210 + t + k * 64;
            if (i < OBS) sb[S_OBS + i] = orow[i];
        }
    }
    __syncthreads();
    if (t < 20) {
        const float* nb = &sb[S_OBS + 242 + t * 22];
        int id = (int)nb[0], js = -1;
        #pragma unroll
        for (int j = 0; j < ACTN; ++j) {
            float av = nb[1 + j];
            js = (av != 0.f && js < 0) ? j : js;
        }
        int mode = (id < -1) ? 0 : ((id >= 0 && js < 0) ? 1 : 2);
        s_meta[t] = ((id + 2) << 8) | (mode << 5) | (js + 1);
    }
    {
        const int oc = t & 31, s = t >> 5;
        float acc[12];
        #pragma unroll
        for (int i = 0; i < 12; ++i) acc[i] = 0.f;
        #pragma unroll
        for (int c = 0; c < 5; ++c) {
            float wv[9];
            #pragma unroll
            for (int k = 0; k < 9; ++k) wv[k] = c1w[oc * 45 + c * 9 + k];
            #pragma unroll
            for (int rr = 0; rr < 5; ++rr) {
                const float* rowp = &sb[S_V + c * 56 + (2 * s + rr) * 8];
                float4 v0 = *(const float4*)rowp;
                float2 v1 = *(const float2*)(rowp + 4);
                float c0 = v0.x, c1 = v0.y, c2 = v0.z, c3 = v0.w, c4 = v1.x, c5 = v1.y;
                #pragma unroll
                for (int kh = 0; kh < 3; ++kh) {
                    int ohl = rr - kh;
                    if (ohl < 0 || ohl > 2) continue;
                    acc[ohl*4+0] = fmaf(c0, wv[kh*3+0], acc[ohl*4+0]);
                    acc[ohl*4+0] = fmaf(c1, wv[kh*3+1], acc[ohl*4+0]);
                    acc[ohl*4+0] = fmaf(c2, wv[kh*3+2], acc[ohl*4+0]);
                    acc[ohl*4+1] = fmaf(c1, wv[kh*3+0], acc[ohl*4+1]);
                    acc[ohl*4+1] = fmaf(c2, wv[kh*3+1], acc[ohl*4+1]);
                    acc[ohl*4+1] = fmaf(c3, wv[kh*3+2], acc[ohl*4+1]);
                    acc[ohl*4+2] = fmaf(c2, wv[kh*3+0], acc[ohl*4+2]);
                    acc[ohl*4+2] = fmaf(c3, wv[kh*3+1], acc[ohl*4+2]);
                    acc[ohl*4+2] = fmaf(c4, wv[kh*3+2], acc[ohl*4+2]);
                    acc[ohl*4+3] = fmaf(c3, wv[kh*3+0], acc[ohl*4+3]);
                    acc[ohl*4+3] = fmaf(c4, wv[kh*3+1], acc[ohl*4+3]);
                    acc[ohl*4+3] = fmaf(c5, wv[kh*3+2], acc[ohl*4+3]);
                }
            }
        }
        float bias = c1b[oc];
        #pragma unroll
        for (int ohl = 0; ohl < 3; ++ohl) {
            int oh = 2 * s + ohl;
            float4 o4 = make_float4(fmaxf(acc[ohl*4+0] + bias, 0.f), fmaxf(acc[ohl*4+1] + bias, 0.f),
                                    fmaxf(acc[ohl*4+2] + bias, 0.f), fmaxf(acc[ohl*4+3] + bias, 0.f));
            *(float4*)&sb[S_C1 + oc * 20 + oh * 4] = o4;
        }
    }
    __syncthreads();
    {
        const int oc = t & 31, half = t >> 5;
        float a0=0,a1=0,a2=0,a3=0,a4=0,a5=0;
        #pragma unroll 4
        for (int icc = 0; icc < 16; ++icc) {
            const int ic = half * 16 + icc;
            const float4* rp = (const float4*)&sb[S_C1 + ic * 20];
            float4 r0 = rp[0], r1 = rp[1], r2 = rp[2], r3 = rp[3], r4 = rp[4];
            float wv[9];
            #pragma unroll
            for (int k = 0; k < 9; ++k) wv[k] = c2w[oc * 288 + ic * 9 + k];
            #pragma unroll
            for (int kh = 0; kh < 3; ++kh) {
                float4 ra = (kh == 0) ? r0 : (kh == 1) ? r1 : r2;
                float4 rb = (kh == 0) ? r1 : (kh == 1) ? r2 : r3;
                float4 rc = (kh == 0) ? r2 : (kh == 1) ? r3 : r4;
                #pragma unroll
                for (int kw = 0; kw < 3; ++kw) {
                    float ww = wv[kh * 3 + kw];
                    a0 = fmaf(comp4(ra, kw),     ww, a0);
                    a1 = fmaf(comp4(ra, kw + 1), ww, a1);
                    a2 = fmaf(comp4(rb, kw),     ww, a2);
                    a3 = fmaf(comp4(rb, kw + 1), ww, a3);
                    a4 = fmaf(comp4(rc, kw),     ww, a4);
                    a5 = fmaf(comp4(rc, kw + 1), ww, a5);
                }
            }
        }
        float* pp = &sb[S_PART + (half * 32 + oc) * 6];
        pp[0]=a0; pp[1]=a1; pp[2]=a2; pp[3]=a3; pp[4]=a4; pp[5]=a5;
    }
    __syncthreads();
    if (t < 32) {
        float bias = c2b[t];
        #pragma unroll
        for (int p = 0; p < 6; ++p)
            sb[S_C2 + t * 6 + p] = fmaxf(sb[S_PART + t * 6 + p] + sb[S_PART + (32 + t) * 6 + p] + bias, 0.f);
    }
    __syncthreads();
    {
        float a0 = f1b[t], a1 = 0.f;
        const float4* xp = (const float4*)&sb[S_C2];
        #pragma unroll 4
        for (int kq = 0; kq < 48; ++kq) {
            float4 x = xp[kq];
            a0 = fmaf(x.x, f1w[(4*kq+0)*64+t], a0);
            a1 = fmaf(x.y, f1w[(4*kq+1)*64+t], a1);
            a0 = fmaf(x.z, f1w[(4*kq+2)*64+t], a0);
            a1 = fmaf(x.w, f1w[(4*kq+3)*64+t], a1);
        }
        sb[S_X + t] = fmaxf(a0 + a1, 0.f);
    }
    __syncthreads();
    float base_t;
    {
        float a0 = f2b[t], a1 = 0.f;
        const float4* xp = (const float4*)&sb[S_X];
        #pragma unroll 4
        for (int kq = 0; kq < 16; ++kq) {
            float4 x = xp[kq];
            a0 = fmaf(x.x, f2w[(4*kq+0)*64+t], a0);
            a1 = fmaf(x.y, f2w[(4*kq+1)*64+t], a1);
            a0 = fmaf(x.z, f2w[(4*kq+2)*64+t], a0);
            a1 = fmaf(x.w, f2w[(4*kq+3)*64+t], a1);
        }
        const float2* fp = (const float2*)&sb[S_OBS + 210];
        #pragma unroll 4
        for (int i2 = 0; i2 < 16; ++i2) {
            float2 v = fp[i2];
            a0 = fmaf(v.x, f2w[(64 + i2*2+0)*64+t], a0);
            a1 = fmaf(v.y, f2w[(64 + i2*2+1)*64+t], a1);
        }
        base_t = a0 + a1;
    }
    const float* W2id = f2w + 96 * 64;
    const float* W2act = f2w + 116 * 64;
    float hacc = 0.f, cnt = 0.f;
    for (int a = 0; a < 20; ++a) {
        int m = s_meta[a];
        int mode = (m >> 5) & 3;
        if (mode == 0) continue;
        int id = (m >> 8) - 2, js = (m & 31) - 1;
        float u = base_t + ((id >= 0) ? W2id[id * 64 + t] : 0.f);
        if (mode == 1) {
            float h0=0,h1=0,h2=0;
            #pragma unroll
            for (int j = 0; j < ACTN; j += 3) {
                h0 += fmaxf(u + W2act[(j    )*64+t], 0.f);
                h1 += fmaxf(u + W2act[(j + 1)*64+t], 0.f);
                h2 += fmaxf(u + W2act[(j + 2)*64+t], 0.f);
            }
            hacc += (h0 + h1) + h2; cnt += 21.f;
        } else {
            float ar = (js >= 0) ? W2act[js * 64 + t] : 0.f;
            hacc += fmaxf(u + ar, 0.f); cnt += 1.f;
        }
    }
    sb[S_H + t] = hacc;
    __syncthreads();
    if (t < ACTN) {
        float q0 = cnt * f3b[t], q1 = 0.f;
        const float4* hp = (const float4*)&sb[S_H];
        #pragma unroll 4
        for (int h4 = 0; h4 < 16; ++h4) {
            float4 v = hp[h4];
            q0 = fmaf(v.x, f3w[(h4*4+0)*21+t], q0);
            q1 = fmaf(v.y, f3w[(h4*4+1)*21+t], q1);
            q0 = fmaf(v.z, f3w[(h4*4+2)*21+t], q0);
            q1 = fmaf(v.w, f3w[(h4*4+3)*21+t], q1);
        }
        out[b * 21 + t] = q0 + q1;
    }
}

extern "C" void kernel_launch(void* const* d_in, const int* in_sizes, int n_in,
                              void* d_out, int out_size, void* d_ws, size_t ws_size,
                              hipStream_t stream) {
    const float* obs = (const float*)d_in[0];
    const float* c1w = (const float*)d_in[1];
    const float* c1b = (const float*)d_in[2];
    const float* c2w = (const float*)d_in[3];
    const float* c2b = (const float*)d_in[4];
    const float* f1w = (const float*)d_in[5];
    const float* f1b = (const float*)d_in[6];
    const float* f2w = (const float*)d_in[7];
    const float* f2b = (const float*)d_in[8];
    const float* f3w = (const float*)d_in[9];
    const float* f3b = (const float*)d_in[10];
    float* o = (float*)d_out;
    const int B = in_sizes[0] / OBS;

    if (ws_size >= (size_t)WS_TOTU * 2 && (B % MB) == 0) {
        unsigned short* wsu = (unsigned short*)d_ws;
        repack_b<<<(WS_TOTU + 255) / 256, 256, 0, stream>>>(c1w, c2w, f1w, wsu);
        mfma_k<<<B / MB, 512, 0, stream>>>(obs, c1b, c2b, f1b, f2w, f2b, f3w, f3b, wsu, o);
    } else {
        fallback_k<<<B, 64, 0, stream>>>(obs, c1w, c1b, c2w, c2b, f1w, f1b,
                                         f2w, f2b, f3w, f3b, o);
    }
}

// Round 10
// 28.931 us; speedup vs baseline: 1.6399x; 1.0368x over previous
//
#include <hip/hip_runtime.h>

typedef __attribute__((ext_vector_type(8))) short bf16x8;
typedef __attribute__((ext_vector_type(4))) float f32x4;

constexpr int OBS  = 682;
constexpr int ACTN = 21;
constexpr int MB   = 8;           // rows per block

// ---- ws (ushort units): bf16 B-fragments, 512 ushorts per 16x16x32 frag ----
constexpr int WS_C1U  = 0;        // conv1: K=64(pad from 45), N=32 -> 2s x 2nt = 4 frags
constexpr int WS_C2U  = 2048;     // conv2: K=288, N=32 -> 9s x 2nt = 18 frags
constexpr int WS_F1U  = 11264;    // fc1:   K=192, N=64 -> 6s x 4nt = 24 frags
constexpr int WS_TOTU = 23552;    // 46 frags

__device__ __forceinline__ unsigned short f2bf(float x) {
    unsigned u = __float_as_uint(x);
    return (unsigned short)((u + 0x7FFFu + ((u >> 16) & 1u)) >> 16);
}

__global__ void repack_b(const float* __restrict__ c1w, const float* __restrict__ c2w,
                         const float* __restrict__ f1w, unsigned short* __restrict__ wsu) {
    int i = blockIdx.x * 256 + threadIdx.x;
    if (i >= WS_TOTU) return;
    int frag = i >> 9, within = i & 511;
    int l = within >> 3, j = within & 7;
    int q = l >> 4, l15 = l & 15;
    float v = 0.f;
    if (frag < 4) {                          // conv1 B[k<45 pad64][oc32]
        int s = frag >> 1, nt = frag & 1;
        int k = 32 * s + 8 * q + j, n = 16 * nt + l15;
        if (k < 45) v = c1w[n * 45 + k];
    } else if (frag < 22) {                  // conv2 B[288][32]
        int f = frag - 4, s = f >> 1, nt = f & 1;
        int k = 32 * s + 8 * q + j, n = 16 * nt + l15;
        v = c2w[n * 288 + k];
    } else {                                 // fc1 B[192][64]
        int f = frag - 22, s = f >> 2, nt = f & 3;
        int k = 32 * s + 8 * q + j, n = 16 * nt + l15;
        v = f1w[k * 64 + n];
    }
    wsu[i] = f2bf(v);
}

__global__ __launch_bounds__(512, 6) void mfma_k(
    const float* __restrict__ obs,
    const float* __restrict__ c1b, const float* __restrict__ c2b,
    const float* __restrict__ f1b, const float* __restrict__ f2w,
    const float* __restrict__ f2b, const float* __restrict__ f3w,
    const float* __restrict__ f3b,
    const unsigned short* __restrict__ wsu,
    float* __restrict__ out)
{
    const int t = threadIdx.x;
    const int w = t >> 6, l = t & 63;
    const int q = l >> 4, l15 = l & 15;
    const int b8 = blockIdx.x * MB;

    __shared__ __align__(16) unsigned short sv[MB * 280];   // view bf16 [row][c*56+r*8+col]
    __shared__ __align__(16) unsigned short uA[7680];       // A1[160][48] then A2[48][160]
    __shared__ __align__(16) unsigned short sc1[MB * 640];  // bf16 [row][ic*20+pos]; sc2 overlays
    __shared__ __align__(16) float sfeat32[MB * 32];
    __shared__ __align__(16) float sx32[MB * 64];           // fp32 x; sh32 overlays
    __shared__ __align__(16) float sW[2624];                // W2id[20][64] | W2act[21][64]
    __shared__ __align__(16) float sbias[224];              // c1b|c2b|f1b|f2b|f3b
    __shared__ int smeta[MB * 20];
    __shared__ unsigned short tap1[48], tap2[288], mb2[MB * 6];

    unsigned short* sc2 = sc1;        // overlay: sc1 dead after conv2 staging
    float* sh32 = sx32;               // overlay: sx32 dead after base (wave-row-local)

    // ================= phase 0: staging + tables + meta =================
    for (int e = t; e < MB * 210; e += 512) {               // view -> bf16 padded
        int row = e / 210, i2 = e - row * 210;
        int c = i2 / 42, rem = i2 - c * 42;
        int r3 = rem / 6, col = rem - r3 * 6;
        sv[row * 280 + c * 56 + r3 * 8 + col] = f2bf(obs[(long)(b8 + row) * OBS + i2]);
    }
    if (t < MB * 32) {                                       // feat -> fp32
        int row = t >> 5, j = t & 31;
        sfeat32[t] = obs[(long)(b8 + row) * OBS + 210 + j];
    }
    {                                                        // agent weights fp32 -> LDS
        const float4* srcw = (const float4*)(f2w + 96 * 64); // W2id|W2act 2624 floats
        float4* dw = (float4*)sW;
        if (t < 512) { dw[t] = srcw[t]; if (t < 144) dw[512 + t] = srcw[512 + t]; }
    }
    if (t < 224) {
        float v = 0.f;
        if (t < 32) v = c1b[t];
        else if (t < 64) v = c2b[t - 32];
        else if (t < 128) v = f1b[t - 64];
        else if (t < 192) v = f2b[t - 128];
        else if (t < 213) v = f3b[t - 192];
        sbias[t] = v;
    }
    if (t < 48) {
        int c = t / 9, rem = t - c * 9;
        tap1[t] = (unsigned short)(c * 56 + (rem / 3) * 8 + (rem % 3));
    }
    if (t < 288) {
        int ic = t / 9, rem = t - ic * 9;
        tap2[t] = (unsigned short)(ic * 20 + (rem / 3) * 4 + (rem % 3));
    }
    if (t < MB * 6) {
        int row = t / 6, pos = t - row * 6;
        mb2[t] = (unsigned short)(row * 640 + (pos >> 1) * 4 + (pos & 1));
    }
    if (t < MB * 20) {                                       // meta (exact fp32 from global)
        int row = t / 20, a = t - row * 20;
        const float* nb = obs + (long)(b8 + row) * OBS + 242 + a * 22;
        int id = (int)nb[0];
        int js = -1;
        #pragma unroll
        for (int j = 0; j < ACTN; ++j) {
            float av = nb[1 + j];
            js = (av != 0.f && js < 0) ? j : js;
        }
        int mode = (id < -1) ? 0 : ((id >= 0 && js < 0) ? 1 : 2);
        smeta[t] = ((id + 2) << 8) | (mode << 5) | (js + 1);
    }
    __syncthreads();

    // ================= phase 1: A1[160][48] (k>=45 zero) =================
    for (int e = t; e < 160 * 45; e += 512) {
        int rowm = e / 45, k = e - rowm * 45;
        int brow = rowm / 20, pos = rowm - brow * 20;
        int base = brow * 280 + (pos >> 2) * 8 + (pos & 3);
        uA[rowm * 48 + k] = sv[base + tap1[k]];
    }
    if (t < 480) {
        int rowm = t / 3, k = 45 + (t % 3);
        uA[rowm * 48 + k] = 0;
    }
    __syncthreads();

    // ================= phase 2: conv1 MFMA (M160 N32, 20 tiles) =================
    {
        #pragma unroll
        for (int u = 0; u < 3; ++u) {
            int p = w + 8 * u;                  // tile = mt*2+nt
            if (p < 20) {
                int mt = p >> 1, nt = p & 1;
                f32x4 acc = {0.f, 0.f, 0.f, 0.f};
                {   // s = 0: k 0..31
                    bf16x8 a = *(const bf16x8*)&uA[(mt * 16 + l15) * 48 + 8 * q];
                    bf16x8 bb = *(const bf16x8*)&wsu[WS_C1U + (0 + nt) * 512 + l * 8];
                    acc = __builtin_amdgcn_mfma_f32_16x16x32_bf16(a, bb, acc, 0, 0, 0);
                }
                {   // s = 1: k 32..63 ; q>=2 (k>=48) -> register zero (B is zero too)
                    bf16x8 a = {0, 0, 0, 0, 0, 0, 0, 0};
                    if (q < 2) a = *(const bf16x8*)&uA[(mt * 16 + l15) * 48 + 32 + 8 * q];
                    bf16x8 bb = *(const bf16x8*)&wsu[WS_C1U + (2 + nt) * 512 + l * 8];
                    acc = __builtin_amdgcn_mfma_f32_16x16x32_bf16(a, bb, acc, 0, 0, 0);
                }
                int oc = nt * 16 + l15;
                float bias = sbias[oc];
                #pragma unroll
                for (int r = 0; r < 4; ++r) {
                    int m = mt * 16 + 4 * q + r;
                    int row = m / 20, pos = m - row * 20;
                    sc1[row * 640 + oc * 20 + pos] = f2bf(fmaxf(acc[r] + bias, 0.f));
                }
            }
        }
    }
    __syncthreads();

    // ================= phase 3a: A2[48][160] stage a (k 0..159) =================
    for (int e = t; e < 48 * 160; e += 512) {
        int m = e / 160, k = e - m * 160;
        uA[m * 160 + k] = sc1[mb2[m] + tap2[k]];
    }
    __syncthreads();

    // ================= phase 4a: conv2 partial (s 0..4) =================
    f32x4 c2acc = {0.f, 0.f, 0.f, 0.f};
    const bool c2act = (w < 6);
    const int c2mt = w >> 1, c2nt = w & 1;
    if (c2act) {
        #pragma unroll
        for (int s = 0; s < 5; ++s) {
            bf16x8 a = *(const bf16x8*)&uA[(c2mt * 16 + l15) * 160 + 32 * s + 8 * q];
            bf16x8 bb = *(const bf16x8*)&wsu[WS_C2U + (s * 2 + c2nt) * 512 + l * 8];
            c2acc = __builtin_amdgcn_mfma_f32_16x16x32_bf16(a, bb, c2acc, 0, 0, 0);
        }
    }
    __syncthreads();

    // ================= phase 3b: A2 stage b (k 160..287 -> cols 0..127) =================
    for (int e = t; e < 48 * 128; e += 512) {
        int m = e >> 7, k2 = e & 127;
        uA[m * 160 + k2] = sc1[mb2[m] + tap2[160 + k2]];
    }
    __syncthreads();

    // ================= phase 4b: conv2 finish (s 5..8) + store sc2 =================
    if (c2act) {
        #pragma unroll
        for (int s = 5; s < 9; ++s) {
            bf16x8 a = *(const bf16x8*)&uA[(c2mt * 16 + l15) * 160 + 32 * (s - 5) + 8 * q];
            bf16x8 bb = *(const bf16x8*)&wsu[WS_C2U + (s * 2 + c2nt) * 512 + l * 8];
            c2acc = __builtin_amdgcn_mfma_f32_16x16x32_bf16(a, bb, c2acc, 0, 0, 0);
        }
        int oc = c2nt * 16 + l15;
        float bias = sbias[32 + oc];
        #pragma unroll
        for (int r = 0; r < 4; ++r) {
            int m = c2mt * 16 + 4 * q + r;
            int row = m / 6, pos = m - row * 6;
            sc2[row * 200 + oc * 6 + pos] = f2bf(fmaxf(c2acc[r] + bias, 0.f));
        }
    }
    __syncthreads();

    // ================= phase 5: fc1 MFMA (M16(8 valid) N64 K192) -> fp32 x ======
    if (w < 4) {
        int nt = w;
        f32x4 acc = {0.f, 0.f, 0.f, 0.f};
        #pragma unroll
        for (int s = 0; s < 6; ++s) {
            bf16x8 a = *(const bf16x8*)&sc2[l15 * 200 + 32 * s + 8 * q];
            bf16x8 bb = *(const bf16x8*)&wsu[WS_F1U + (s * 4 + nt) * 512 + l * 8];
            acc = __builtin_amdgcn_mfma_f32_16x16x32_bf16(a, bb, acc, 0, 0, 0);
        }
        int h = nt * 16 + l15;
        float bias = sbias[64 + h];
        #pragma unroll
        for (int r = 0; r < 4; ++r) {
            int row = 4 * q + r;
            if (row < MB) sx32[row * 64 + h] = fmaxf(acc[r] + bias, 0.f);
        }
    }
    __syncthreads();

    // ============ phases 6+7: base + agents, wave-row-local (row = w) ============
    float cnt;
    {
        const int row = w;
        // base (fp32, exact); W2x/W2f read directly from global (L2-resident)
        float a0 = sbias[128 + l], a1 = 0.f;
        #pragma unroll 4
        for (int k = 0; k < 64; k += 2) {
            a0 = fmaf(sx32[row * 64 + k],     f2w[(k    ) * 64 + l], a0);
            a1 = fmaf(sx32[row * 64 + k + 1], f2w[(k + 1) * 64 + l], a1);
        }
        #pragma unroll 4
        for (int k = 0; k < 32; k += 2) {
            a0 = fmaf(sfeat32[row * 32 + k],     f2w[(64 + k    ) * 64 + l], a0);
            a1 = fmaf(sfeat32[row * 32 + k + 1], f2w[(64 + k + 1) * 64 + l], a1);
        }
        const float base_l = a0 + a1;
        // agents (fp32, exact logic; W2id/W2act from LDS)
        float hacc = 0.f;
        cnt = 0.f;
        for (int a = 0; a < 20; ++a) {
            int m = smeta[row * 20 + a];
            int mode = (m >> 5) & 3;
            if (mode == 0) continue;
            int id = (m >> 8) - 2;
            int js = (m & 31) - 1;
            float u = base_l + ((id >= 0) ? sW[id * 64 + l] : 0.f);
            if (mode == 1) {                 // expand: sum_j relu(u + W2act[j])
                float h0 = 0.f, h1 = 0.f, h2 = 0.f;
                #pragma unroll
                for (int j = 0; j < ACTN; j += 3) {
                    h0 += fmaxf(u + sW[1280 + (j    ) * 64 + l], 0.f);
                    h1 += fmaxf(u + sW[1280 + (j + 1) * 64 + l], 0.f);
                    h2 += fmaxf(u + sW[1280 + (j + 2) * 64 + l], 0.f);
                }
                hacc += (h0 + h1) + h2;
                cnt  += 21.f;
            } else {
                float ar = (js >= 0) ? sW[1280 + js * 64 + l] : 0.f;
                hacc += fmaxf(u + ar, 0.f);
                cnt  += 1.f;
            }
        }
        sh32[row * 64 + l] = hacc;           // overlay over sx32 (own row, read done)
    }
    // NOTE: no barrier — phase 8 reads only row w, written by this wave.

    // ================= phase 8: fc3 fp32 + store (row = w) =================
    if (l < ACTN) {
        float qv = cnt * sbias[192 + l];     // cnt is wave-uniform, in register
        float q1 = 0.f;
        #pragma unroll 4
        for (int h = 0; h < 64; h += 2) {
            qv = fmaf(sh32[w * 64 + h],     f3w[(h    ) * 21 + l], qv);
            q1 = fmaf(sh32[w * 64 + h + 1], f3w[(h + 1) * 21 + l], q1);
        }
        out[(long)(b8 + w) * 21 + l] = qv + q1;
    }
}

// ================= fallback: R6 structure, raw weights (no ws) =================
__device__ __forceinline__ float comp4(float4 v, int i) {
    return (i == 0) ? v.x : (i == 1) ? v.y : (i == 2) ? v.z : v.w;
}

constexpr int S_V = 0, S_OBS = 280, S_C1 = 968, S_PART = 1608, S_C2 = 1992,
              S_X = 2184, S_H = 2248, S_TOT = 2312;

__global__ __launch_bounds__(64, 4) void fallback_k(
    const float* __restrict__ obs,
    const float* __restrict__ c1w, const float* __restrict__ c1b,
    const float* __restrict__ c2w, const float* __restrict__ c2b,
    const float* __restrict__ f1w, const float* __restrict__ f1b,
    const float* __restrict__ f2w, const float* __restrict__ f2b,
    const float* __restrict__ f3w, const float* __restrict__ f3b,
    float* __restrict__ out)
{
    const int b = blockIdx.x, t = threadIdx.x;
    __shared__ __align__(16) float sb[S_TOT];
    __shared__ int s_meta[20];
    {
        const float* orow = obs + (long)b * OBS;
        #pragma unroll
        for (int k = 0; k < 4; ++k) {
            int i = t + k * 64;
            if (i < 210) {
                int c = i / 42, rem = i - 42 * c, r = rem / 6, col = rem - 6 * r;
                sb[S_V + c * 56 + r * 8 + col] = orow[i];
            }
        }
        #pragma unroll
        for (int k = 0; k < 8; ++k) {
            int i = 210 + t + k * 64;
            if (i < OBS) sb[S_OBS + i] = orow[i];
        }
    }
    __syncthreads();
    if (t < 20) {
        const float* nb = &sb[S_OBS + 242 + t * 22];
        int id = (int)nb[0], js = -1;
        #pragma unroll
        for (int j = 0; j < ACTN; ++j) {
            float av = nb[1 + j];
            js = (av != 0.f && js < 0) ? j : js;
        }
        int mode = (id < -1) ? 0 : ((id >= 0 && js < 0) ? 1 : 2);
        s_meta[t] = ((id + 2) << 8) | (mode << 5) | (js + 1);
    }
    {
        const int oc = t & 31, s = t >> 5;
        float acc[12];
        #pragma unroll
        for (int i = 0; i < 12; ++i) acc[i] = 0.f;
        #pragma unroll
        for (int c = 0; c < 5; ++c) {
            float wv[9];
            #pragma unroll
            for (int k = 0; k < 9; ++k) wv[k] = c1w[oc * 45 + c * 9 + k];
            #pragma unroll
            for (int rr = 0; rr < 5; ++rr) {
                const float* rowp = &sb[S_V + c * 56 + (2 * s + rr) * 8];
                float4 v0 = *(const float4*)rowp;
                float2 v1 = *(const float2*)(rowp + 4);
                float c0 = v0.x, c1 = v0.y, c2 = v0.z, c3 = v0.w, c4 = v1.x, c5 = v1.y;
                #pragma unroll
                for (int kh = 0; kh < 3; ++kh) {
                    int ohl = rr - kh;
                    if (ohl < 0 || ohl > 2) continue;
                    acc[ohl*4+0] = fmaf(c0, wv[kh*3+0], acc[ohl*4+0]);
                    acc[ohl*4+0] = fmaf(c1, wv[kh*3+1], acc[ohl*4+0]);
                    acc[ohl*4+0] = fmaf(c2, wv[kh*3+2], acc[ohl*4+0]);
                    acc[ohl*4+1] = fmaf(c1, wv[kh*3+0], acc[ohl*4+1]);
                    acc[ohl*4+1] = fmaf(c2, wv[kh*3+1], acc[ohl*4+1]);
                    acc[ohl*4+1] = fmaf(c3, wv[kh*3+2], acc[ohl*4+1]);
                    acc[ohl*4+2] = fmaf(c2, wv[kh*3+0], acc[ohl*4+2]);
                    acc[ohl*4+2] = fmaf(c3, wv[kh*3+1], acc[ohl*4+2]);
                    acc[ohl*4+2] = fmaf(c4, wv[kh*3+2], acc[ohl*4+2]);
                    acc[ohl*4+3] = fmaf(c3, wv[kh*3+0], acc[ohl*4+3]);
                    acc[ohl*4+3] = fmaf(c4, wv[kh*3+1], acc[ohl*4+3]);
                    acc[ohl*4+3] = fmaf(c5, wv[kh*3+2], acc[ohl*4+3]);
                }
            }
        }
        float bias = c1b[oc];
        #pragma unroll
        for (int ohl = 0; ohl < 3; ++ohl) {
            int oh = 2 * s + ohl;
            float4 o4 = make_float4(fmaxf(acc[ohl*4+0] + bias, 0.f), fmaxf(acc[ohl*4+1] + bias, 0.f),
                                    fmaxf(acc[ohl*4+2] + bias, 0.f), fmaxf(acc[ohl*4+3] + bias, 0.f));
            *(float4*)&sb[S_C1 + oc * 20 + oh * 4] = o4;
        }
    }
    __syncthreads();
    {
        const int oc = t & 31, half = t >> 5;
        float a0=0,a1=0,a2=0,a3=0,a4=0,a5=0;
        #pragma unroll 4
        for (int icc = 0; icc < 16; ++icc) {
            const int ic = half * 16 + icc;
            const float4* rp = (const float4*)&sb[S_C1 + ic * 20];
            float4 r0 = rp[0], r1 = rp[1], r2 = rp[2], r3 = rp[3], r4 = rp[4];
            float wv[9];
            #pragma unroll
            for (int k = 0; k < 9; ++k) wv[k] = c2w[oc * 288 + ic * 9 + k];
            #pragma unroll
            for (int kh = 0; kh < 3; ++kh) {
                float4 ra = (kh == 0) ? r0 : (kh == 1) ? r1 : r2;
                float4 rb = (kh == 0) ? r1 : (kh == 1) ? r2 : r3;
                float4 rc = (kh == 0) ? r2 : (kh == 1) ? r3 : r4;
                #pragma unroll
                for (int kw = 0; kw < 3; ++kw) {
                    float ww = wv[kh * 3 + kw];
                    a0 = fmaf(comp4(ra, kw),     ww, a0);
                    a1 = fmaf(comp4(ra, kw + 1), ww, a1);
                    a2 = fmaf(comp4(rb, kw),     ww, a2);
                    a3 = fmaf(comp4(rb, kw + 1), ww, a3);
                    a4 = fmaf(comp4(rc, kw),     ww, a4);
                    a5 = fmaf(comp4(rc, kw + 1), ww, a5);
                }
            }
        }
        float* pp = &sb[S_PART + (half * 32 + oc) * 6];
        pp[0]=a0; pp[1]=a1; pp[2]=a2; pp[3]=a3; pp[4]=a4; pp[5]=a5;
    }
    __syncthreads();
    if (t < 32) {
        float bias = c2b[t];
        #pragma unroll
        for (int p = 0; p < 6; ++p)
            sb[S_C2 + t * 6 + p] = fmaxf(sb[S_PART + t * 6 + p] + sb[S_PART + (32 + t) * 6 + p] + bias, 0.f);
    }
    __syncthreads();
    {
        float a0 = f1b[t], a1 = 0.f;
        const float4* xp = (const float4*)&sb[S_C2];
        #pragma unroll 4
        for (int kq = 0; kq < 48; ++kq) {
            float4 x = xp[kq];
            a0 = fmaf(x.x, f1w[(4*kq+0)*64+t], a0);
            a1 = fmaf(x.y, f1w[(4*kq+1)*64+t], a1);
            a0 = fmaf(x.z, f1w[(4*kq+2)*64+t], a0);
            a1 = fmaf(x.w, f1w[(4*kq+3)*64+t], a1);
        }
        sb[S_X + t] = fmaxf(a0 + a1, 0.f);
    }
    __syncthreads();
    float base_t;
    {
        float a0 = f2b[t], a1 = 0.f;
        const float4* xp = (const float4*)&sb[S_X];
        #pragma unroll 4
        for (int kq = 0; kq < 16; ++kq) {
            float4 x = xp[kq];
            a0 = fmaf(x.x, f2w[(4*kq+0)*64+t], a0);
            a1 = fmaf(x.y, f2w[(4*kq+1)*64+t], a1);
            a0 = fmaf(x.z, f2w[(4*kq+2)*64+t], a0);
            a1 = fmaf(x.w, f2w[(4*kq+3)*64+t], a1);
        }
        const float2* fp = (const float2*)&sb[S_OBS + 210];
        #pragma unroll 4
        for (int i2 = 0; i2 < 16; ++i2) {
            float2 v = fp[i2];
            a0 = fmaf(v.x, f2w[(64 + i2*2+0)*64+t], a0);
            a1 = fmaf(v.y, f2w[(64 + i2*2+1)*64+t], a1);
        }
        base_t = a0 + a1;
    }
    const float* W2id = f2w + 96 * 64;
    const float* W2act = f2w + 116 * 64;
    float hacc = 0.f, cnt = 0.f;
    for (int a = 0; a < 20; ++a) {
        int m = s_meta[a];
        int mode = (m >> 5) & 3;
        if (mode == 0) continue;
        int id = (m >> 8) - 2, js = (m & 31) - 1;
        float u = base_t + ((id >= 0) ? W2id[id * 64 + t] : 0.f);
        if (mode == 1) {
            float h0=0,h1=0,h2=0;
            #pragma unroll
            for (int j = 0; j < ACTN; j += 3) {
                h0 += fmaxf(u + W2act[(j    )*64+t], 0.f);
                h1 += fmaxf(u + W2act[(j + 1)*64+t], 0.f);
                h2 += fmaxf(u + W2act[(j + 2)*64+t], 0.f);
            }
            hacc += (h0 + h1) + h2; cnt += 21.f;
        } else {
            float ar = (js >= 0) ? W2act[js * 64 + t] : 0.f;
            hacc += fmaxf(u + ar, 0.f); cnt += 1.f;
        }
    }
    sb[S_H + t] = hacc;
    __syncthreads();
    if (t < ACTN) {
        float q0 = cnt * f3b[t], q1 = 0.f;
        const float4* hp = (const float4*)&sb[S_H];
        #pragma unroll 4
        for (int h4 = 0; h4 < 16; ++h4) {
            float4 v = hp[h4];
            q0 = fmaf(v.x, f3w[(h4*4+0)*21+t], q0);
            q1 = fmaf(v.y, f3w[(h4*4+1)*21+t], q1);
            q0 = fmaf(v.z, f3w[(h4*4+2)*21+t], q0);
            q1 = fmaf(v.w, f3w[(h4*4+3)*21+t], q1);
        }
        out[b * 21 + t] = q0 + q1;
    }
}

extern "C" void kernel_launch(void* const* d_in, const int* in_sizes, int n_in,
                              void* d_out, int out_size, void* d_ws, size_t ws_size,
                              hipStream_t stream) {
    const float* obs = (const float*)d_in[0];
    const float* c1w = (const float*)d_in[1];
    const float* c1b = (const float*)d_in[2];
    const float* c2w = (const float*)d_in[3];
    const float* c2b = (const float*)d_in[4];
    const float* f1w = (const float*)d_in[5];
    const float* f1b = (const float*)d_in[6];
    const float* f2w = (const float*)d_in[7];
    const float* f2b = (const float*)d_in[8];
    const float* f3w = (const float*)d_in[9];
    const float* f3b = (const float*)d_in[10];
    float* o = (float*)d_out;
    const int B = in_sizes[0] / OBS;

    if (ws_size >= (size_t)WS_TOTU * 2 && (B % MB) == 0) {
        unsigned short* wsu = (unsigned short*)d_ws;
        repack_b<<<(WS_TOTU + 255) / 256, 256, 0, stream>>>(c1w, c2w, f1w, wsu);
        mfma_k<<<B / MB, 512, 0, stream>>>(obs, c1b, c2b, f1b, f2w, f2b, f3w, f3b, wsu, o);
    } else {
        fallback_k<<<B, 64, 0, stream>>>(obs, c1w, c1b, c2w, c2b, f1w, f1b,
                                         f2w, f2b, f3w, f3b, o);
    }
}